// Round 8
// baseline (210.865 us; speedup 1.0000x reference)
//
#include <hip/hip_runtime.h>
#include <hip/hip_bf16.h>

// Problem constants
#define BB 8
#define NN 8192
#define CC 64
#define PP 2048
#define KK 16
#define H1 64
#define H2 128
#define K1PAD 160
#define K2PAD 72

typedef float  f32x4 __attribute__((ext_vector_type(4)));
typedef short  s16x8 __attribute__((ext_vector_type(8)));

// ---- workspace layout (bytes) ----
#define OFF_FXT   0u                    // B*N*68 f32 = 17,825,792
#define OFF_PTS4  17825792u             // B*N float4 = 2,097,152
#define OFF_KNN   19922944u             // B*P*16 int  = 1,048,576
#define OFF_W1P   20971520u             // 64*160 bf16 = 20,480
#define OFF_W2P   20992000u             // 128*72 bf16 = 18,432
#define OFF_C1    21010432u             // 64 f32
#define OFF_C2    21010688u             // 128 f32

#define FLTMAX 3.402823466e+38f

static __device__ __forceinline__ unsigned short bf16b(float v) {
    __hip_bfloat16 h = __float2bfloat16(v);
    return *reinterpret_cast<unsigned short*>(&h);
}
static __device__ __forceinline__ unsigned pk2(float a, float b) {
    return ((unsigned)bf16b(b) << 16) | (unsigned)bf16b(a);
}
// wave-local LDS fence: compiler barrier + LDS drain, NO vmcnt drain
#define LDS_FENCE() asm volatile("s_waitcnt lgkmcnt(0)" ::: "memory")

// ---------------- K1 v2: prep + (merged) weight folding ----------------
// Blocks 0..1023: transpose feat -> fxt[b][n][68], pts4, out0, out2.
// Block 1024: fold BN into weights (former k0).
__global__ __launch_bounds__(512) void k1_prep(const float* __restrict__ xyz,
                                               const float* __restrict__ feat,
                                               const float* __restrict__ W1, const float* __restrict__ b1,
                                               const float* __restrict__ g1, const float* __restrict__ be1,
                                               const float* __restrict__ m1, const float* __restrict__ v1,
                                               const float* __restrict__ W2, const float* __restrict__ b2,
                                               const float* __restrict__ g2, const float* __restrict__ be2,
                                               const float* __restrict__ m2, const float* __restrict__ v2,
                                               float* __restrict__ fxt,
                                               float4* __restrict__ pts4,
                                               float* __restrict__ out0,
                                               float* __restrict__ out2,
                                               unsigned short* __restrict__ w1p,
                                               unsigned short* __restrict__ w2p,
                                               float* __restrict__ c1, float* __restrict__ c2) {
    if (blockIdx.x >= 1024) {
        // weight-folding block
        for (int i = threadIdx.x; i < 19648; i += 512) {
            if (i < 64 * K1PAD) {
                int n = i / K1PAD, c = i - n * K1PAD;
                float s = g1[n] * rsqrtf(v1[n] + 1e-5f);
                float val = 0.f;
                if (c < 67)                  val = W1[n * 134 + c] * s;
                else if (c >= 72 && c < 139) val = W1[n * 134 + (c - 5)] * s;
                w1p[i] = bf16b(val);
            } else if (i < 19456) {
                int j = i - 10240;
                int o = j / K2PAD, k = j - o * K2PAD;
                float s = g2[o] * rsqrtf(v2[o] + 1e-5f);
                w2p[j] = bf16b((k < 64) ? W2[o * 64 + k] * s : 0.f);
            } else if (i < 19520) {
                int l = i - 19456;
                float s = g1[l] * rsqrtf(v1[l] + 1e-5f);
                c1[l] = s * (b1[l] - m1[l]) + be1[l];
            } else {
                int p = i - 19520;
                float s = g2[p] * rsqrtf(v2[p] + 1e-5f);
                c2[p] = s * (b2[p] - m2[p]) + be2[p];
            }
        }
        return;
    }
    __shared__ float tile[68][65];
    int b  = blockIdx.x >> 7;
    int n0 = (blockIdx.x & 127) * 64;
    int tx = threadIdx.x & 63, ty = threadIdx.x >> 6;
    for (int c = ty; c < 68; c += 8) {
        float v;
        if (c < 64)       v = feat[((size_t)b * 64 + c) * NN + n0 + tx];
        else if (c < 67)  v = xyz[((size_t)b * NN + n0 + tx) * 3 + (c - 64)];
        else              v = 0.f;
        tile[c][tx] = v;
    }
    __syncthreads();
    size_t base = ((size_t)b * NN + n0) * 68;
    for (int e = threadIdx.x; e < 64 * 68; e += 512) {
        int nl = e / 68, c = e - nl * 68;
        fxt[base + e] = tile[c][nl];
    }
    if (threadIdx.x < 64) {
        int n = n0 + threadIdx.x;
        float x = tile[64][threadIdx.x], y = tile[65][threadIdx.x], z = tile[66][threadIdx.x];
        pts4[(size_t)b * NN + n] = make_float4(x, y, z, x * x + y * y + z * z);
        if (n0 < PP) out2[b * PP + n] = (float)n;
    }
    if (n0 < PP) {
        for (int e = threadIdx.x; e < 64 * 3; e += 512) {
            int nl = e / 3, d = e - nl * 3;
            out0[((size_t)b * PP + n0 + nl) * 3 + d] = tile[64 + d][nl];
        }
    }
}

// ---------------- K2 v6: exact KNN, wave-pair candidate split, Q=8/wave ----
// 256 blocks x 1024 thr (16 waves). Wave pair (p, p+8) serves the same 8
// queries; wave p scans rows 0..63, wave p+8 rows 64..127 (1 row = 64 cand
// per lane -> 64 ds_read_b128/wave, HALF of v5, same VALU). T(q) =
// min(own 16th-quantile, partner's) — both valid upper bounds on d16.
// Compaction into pair-shared scratch (LDS atomic reservation); rank-select
// split: wave h handles query pr+h (2 survivors/lane, cap 128).
__global__ __launch_bounds__(1024, 4) void k2_knn(const float4* __restrict__ pts4,
                                                  int* __restrict__ knn) {
    __shared__ float4 stage[8192];            // 128 KB
    __shared__ float2 scratch[8][2][128];     // 16 KB pair-shared survivors
    __shared__ float  Tbuf[16][8];            // per-wave 16th quantiles
    __shared__ int    cnt[8][2];
    int lane = threadIdx.x & 63;
    int wv   = threadIdx.x >> 6;
    int pair = wv & 7;
    int half = wv >> 3;
    int b    = blockIdx.x >> 5;
    int q0   = (blockIdx.x & 31) * 64 + pair * 8;
    size_t pb = (size_t)b * NN;

    if (threadIdx.x < 16) cnt[threadIdx.x >> 1][threadIdx.x & 1] = 0;

    // query coefficients (8 per wave)
    float4 qc = make_float4(0.f, 0.f, 0.f, 0.f);
    if (lane < 8) qc = pts4[pb + q0 + lane];
    float qx2 = -2.f * qc.x, qy2 = -2.f * qc.y, qz2 = -2.f * qc.z;
    float bx[8], by[8], bz[8];
#pragma unroll
    for (int q = 0; q < 8; ++q) {
        bx[q] = __shfl(qx2, q); by[q] = __shfl(qy2, q); bz[q] = __shfl(qz2, q);
    }

    // stage all 8192 points, swizzled slot(r,c) = r*64 + ((c + (r>>1)) & 63)
#pragma unroll
    for (int i = 0; i < 8; ++i) {
        int p = i * 1024 + threadIdx.x;
        float4 v = pts4[pb + p];
        int r = p >> 6, c = p & 63;
        stage[(r << 6) | ((c + (r >> 1)) & 63)] = v;
    }
    __syncthreads();

    // Phase 1: lane owns row (half*64 + lane), 64 candidates, 8 queries
    int row = half * 64 + lane;
    int rowbase = row << 6;
    float m[8];
#pragma unroll
    for (int q = 0; q < 8; ++q) m[q] = FLTMAX;
#pragma unroll
    for (int j8 = 0; j8 < 8; ++j8) {
        float4 cc[8];
#pragma unroll
        for (int i = 0; i < 8; ++i)
            cc[i] = stage[rowbase | ((j8 * 8 + i + lane) & 63)];
#pragma unroll
        for (int q = 0; q < 8; ++q) {
            float x = bx[q], y = by[q], z = bz[q];
#pragma unroll
            for (int i = 0; i < 8; i += 2) {
                float e0 = fmaf(z, cc[i].z, fmaf(y, cc[i].y, fmaf(x, cc[i].x, cc[i].w)));
                float e1 = fmaf(z, cc[i+1].z, fmaf(y, cc[i+1].y, fmaf(x, cc[i+1].x, cc[i+1].w)));
                m[q] = fminf(fminf(m[q], e0), e1);
            }
        }
    }

    // own 16th-smallest lane-min per query: 8-interleaved value bitonic
    float sv[8];
#pragma unroll
    for (int q = 0; q < 8; ++q) sv[q] = m[q];
#pragma unroll
    for (int k = 2; k <= 64; k <<= 1) {
#pragma unroll
        for (int j = k >> 1; j > 0; j >>= 1) {
            bool keepMin = (((lane & k) == 0) == ((lane & j) == 0));
#pragma unroll
            for (int q = 0; q < 8; ++q) {
                float p = __shfl_xor(sv[q], j, 64);
                sv[q] = keepMin ? fminf(sv[q], p) : fmaxf(sv[q], p);
            }
        }
    }
    if (lane == 0) {
#pragma unroll
        for (int q = 0; q < 8; ++q) Tbuf[wv][q] = 0.f;  // placeholder overwritten below
    }
    float Town[8];
#pragma unroll
    for (int q = 0; q < 8; ++q) Town[q] = __shfl(sv[q], 15, 64);
    if (lane == 0) {
#pragma unroll
        for (int q = 0; q < 8; ++q) Tbuf[wv][q] = Town[q];
    }
    __syncthreads();
    float T[8];
    unsigned long long rm[8];
#pragma unroll
    for (int q = 0; q < 8; ++q) {
        T[q] = fminf(Tbuf[pair][q], Tbuf[pair + 8][q]);
        rm[q] = __ballot(m[q] <= T[q]);
    }

    unsigned long long below = (lane == 63) ? 0x7FFFFFFFFFFFFFFFull
                                            : ((1ull << lane) - 1ull);
#pragma unroll 1
    for (int pr = 0; pr < 8; pr += 2) {
        // rescan both queries of this pair-round into shared scratch
#pragma unroll
        for (int u = 0; u < 2; ++u) {
            int q = pr + u;
            float x = bx[q], y = by[q], z = bz[q], tq = T[q];
            unsigned long long r = rm[q];
            while (r) {
                int sl = __ffsll((long long)r) - 1; r &= r - 1;
                int rw = half * 64 + sl;
                int phys = (lane + sl) & 63;
                float4 c = stage[(rw << 6) | phys];
                float e = fmaf(z, c.z, fmaf(y, c.y, fmaf(x, c.x, c.w)));
                int n = (rw << 6) | ((phys - (rw >> 1)) & 63);
                unsigned long long bal = __ballot(e <= tq);
                if (bal) {
                    int src = __ffsll((long long)bal) - 1;
                    int nsurv = __popcll(bal);
                    int base = 0;
                    if (lane == src) base = atomicAdd(&cnt[pair][u], nsurv);
                    base = __shfl(base, src, 64);
                    if (e <= tq) {
                        int pos = base + __popcll(bal & below);
                        if (pos < 128)
                            scratch[pair][u][pos] = make_float2(e, __int_as_float(n));
                    }
                }
            }
        }
        __syncthreads();
        // rank-select: wave `half` handles query pr+half
        {
            int u = half;
            int M = min(cnt[pair][u], 128);
            float2 own0 = scratch[pair][u][lane];
            float2 own1 = scratch[pair][u][lane + 64];
            float d0 = (lane < M) ? own0.x : FLTMAX;      int n0 = __float_as_int(own0.y);
            float d1 = (lane + 64 < M) ? own1.x : FLTMAX; int n1 = __float_as_int(own1.y);
            int r0 = 0, r1 = 0;
            const float2* buf = &scratch[pair][u][0];
#pragma unroll 4
            for (int j = 0; j < M; ++j) {
                float2 e = buf[j];
                int nj = __float_as_int(e.y);
                r0 += (e.x < d0 || (e.x == d0 && nj < n0)) ? 1 : 0;
                r1 += (e.x < d1 || (e.x == d1 && nj < n1)) ? 1 : 0;
            }
            size_t obase = ((size_t)(b * PP + q0 + pr + u)) * KK;
            if (lane < M && r0 < 16)      knn[obase + r0] = n0;
            if (lane + 64 < M && r1 < 16) knn[obase + r1] = n1;
            if (lane == 0) cnt[pair][u] = 0;   // reset for next pair-round
        }
        __syncthreads();
    }
}

// ---------------- K3 v4: no-spill 4-wave blocks, w1 in LDS, h1 overlay ----
__global__ __launch_bounds__(256, 2) void k3_mlp(const float* __restrict__ fxt,
                                                 const int* __restrict__ knn,
                                                 const unsigned short* __restrict__ w1p,
                                                 const unsigned short* __restrict__ w2p,
                                                 const float* __restrict__ c1,
                                                 const float* __restrict__ c2,
                                                 float* __restrict__ out1) {
    __shared__ __align__(16) char smem[4 * 5632];
    __shared__ float otile[16][132];
    __shared__ __align__(16) unsigned short w1lds[64 * 168];   // 21,504 B
    int lane = threadIdx.x & 63;
    int wv   = threadIdx.x >> 6;
    int b    = blockIdx.x & 7;        // XCD-aware batch assignment
    int qg   = blockIdx.x >> 3;
    int qbase = qg * 16;
    char* seg = smem + wv * 5632;
    float4* sh_t4 = (float4*)(seg + 5120);
    unsigned* sh_tbd = (unsigned*)(seg + 5392);
    unsigned short* h1l = (unsigned short*)(seg);              // overlaid on E
    const float4* fx4 = (const float4*)fxt;

    int col = lane & 15, quad = lane >> 4;
    int r = lane >> 2, s = lane & 3;

    // stage w1p (64x160) into LDS rows of stride 168 (bank-balanced fragments)
    {
        const unsigned* src = (const unsigned*)w1p;
        unsigned* dst = (unsigned*)w1lds;
        for (int t = threadIdx.x; t < 5120; t += 256) {
            int row = t / 80, c = t - row * 80;
            dst[row * 84 + c] = src[t];
        }
    }

    s16x8 w2f[2][8];
#pragma unroll
    for (int ks = 0; ks < 2; ++ks)
#pragma unroll
        for (int nt = 0; nt < 8; ++nt)
            w2f[ks][nt] = *(const s16x8*)(w2p + (nt * 16 + col) * K2PAD + ks * 32 + quad * 8);
    float c1v[4], c2v[8];
#pragma unroll
    for (int nt = 0; nt < 4; ++nt) c1v[nt] = c1[nt * 16 + col];
#pragma unroll
    for (int nt = 0; nt < 8; ++nt) c2v[nt] = c2[nt * 16 + col];

    // all 64 knn indices for this wave's 4 queries (contiguous load)
    int idxAll = knn[((size_t)(b * PP + qbase + wv * 4)) * KK + lane];

    __syncthreads();   // w1lds visible to all waves

    float4 cc[2][5];
    float4 tv[2];

#define PREFETCH(buf, qi_) {                                                  \
        int q_ = qbase + wv * 4 + (qi_);                                      \
        tv[buf] = make_float4(0.f, 0.f, 0.f, 0.f);                            \
        if (lane < 17) tv[buf] = fx4[((size_t)b * NN + q_) * 17 + lane];      \
        int nidx_ = __shfl(idxAll, (qi_) * 16 + r, 64);                       \
        const float4* rowp_ = fx4 + ((size_t)b * NN + nidx_) * 17;            \
        cc[buf][0] = rowp_[s];      cc[buf][1] = rowp_[4 + s];                \
        cc[buf][2] = rowp_[8 + s];  cc[buf][3] = rowp_[12 + s];               \
        cc[buf][4] = rowp_[16]; }

    PREFETCH(0, 0);

#pragma unroll
    for (int qi = 0; qi < 4; ++qi) {
        int cur = qi & 1, nxt = cur ^ 1;
        // stage t row
        if (lane < 17) {
            float4 v = tv[cur];
            sh_t4[lane] = v;
            sh_tbd[lane * 2]     = pk2(v.x, v.y);
            sh_tbd[lane * 2 + 1] = pk2(v.z, v.w);
        }
        LDS_FENCE();
        // build E row r from prefetched registers + re-zero E K-pads
        char* erow = seg + r * 320;
#pragma unroll
        for (int j = 0; j < 4; ++j) {
            int c4 = j * 4 + s;
            float4 v = cc[cur][j], t = sh_t4[c4];
            *(unsigned*)(erow + c4 * 8)     = pk2(v.x - t.x, v.y - t.y);
            *(unsigned*)(erow + c4 * 8 + 4) = pk2(v.z - t.z, v.w - t.w);
        }
        if (s == 0) {
            float4 v = cc[cur][4], t = sh_t4[16];
            *(unsigned*)(erow + 128) = pk2(v.x - t.x, v.y - t.y);
            *(unsigned*)(erow + 132) = pk2(v.z - t.z, v.w - t.w);
        }
        for (int j = s; j < 34; j += 4)
            *(unsigned*)(erow + 144 + j * 4) = sh_tbd[j];
#pragma unroll
        for (int i = lane; i < 192; i += 64) {            // E pad dwords
            int rr = i / 12, jj = i - rr * 12;
            int dw = (jj < 2) ? (34 + jj) : (68 + jj);
            *(unsigned*)(seg + rr * 320 + dw * 4) = 0u;
        }
        // kick next query's gather while GEMMs run
        if (qi < 3) PREFETCH(nxt, qi + 1);
        LDS_FENCE();
        // GEMM1: h1 = relu(E * W1^T + c1); B-fragments from w1lds
        f32x4 acc1[4];
#pragma unroll
        for (int nt = 0; nt < 4; ++nt) acc1[nt] = (f32x4){0.f, 0.f, 0.f, 0.f};
#pragma unroll
        for (int ks = 0; ks < 5; ++ks) {
            s16x8 a = *(const s16x8*)(seg + col * 320 + ks * 64 + quad * 16);
#pragma unroll
            for (int nt = 0; nt < 4; ++nt) {
                s16x8 bf = *(const s16x8*)(w1lds + (nt * 16 + col) * 168 + ks * 32 + quad * 8);
                acc1[nt] = __builtin_amdgcn_mfma_f32_16x16x32_bf16(a, bf, acc1[nt], 0, 0, 0);
            }
        }
        // write h1 (overlaid on E; E fully consumed by in-order LDS reads)
#pragma unroll
        for (int nt = 0; nt < 4; ++nt) {
#pragma unroll
            for (int rr = 0; rr < 4; ++rr) {
                float y = fmaxf(acc1[nt][rr] + c1v[nt], 0.f);
                h1l[(quad * 4 + rr) * K2PAD + nt * 16 + col] = bf16b(y);
            }
        }
        {   // re-zero h1 K-pad (cols 64..71): 16 rows x 4 dwords, 1/lane
            int rr = lane >> 2, dd = lane & 3;
            *(unsigned*)(seg + rr * 144 + 128 + dd * 4) = 0u;
        }
        LDS_FENCE();
        // GEMM2 + maxpool over 16 edges
        f32x4 acc2[8];
#pragma unroll
        for (int nt = 0; nt < 8; ++nt) acc2[nt] = (f32x4){0.f, 0.f, 0.f, 0.f};
#pragma unroll
        for (int ks = 0; ks < 2; ++ks) {
            s16x8 a = *(const s16x8*)(seg + col * 144 + ks * 64 + quad * 16);
#pragma unroll
            for (int nt = 0; nt < 8; ++nt)
                acc2[nt] = __builtin_amdgcn_mfma_f32_16x16x32_bf16(a, w2f[ks][nt], acc2[nt], 0, 0, 0);
        }
#pragma unroll
        for (int nt = 0; nt < 8; ++nt) {
            float m0 = fmaxf(fmaxf(acc2[nt][0], acc2[nt][1]), fmaxf(acc2[nt][2], acc2[nt][3]));
            m0 = m0 + c2v[nt];
            m0 = fmaxf(m0, 0.f);
            m0 = fmaxf(m0, __shfl_xor(m0, 16, 64));
            m0 = fmaxf(m0, __shfl_xor(m0, 32, 64));
            if (quad == 0)
                otile[wv * 4 + qi][nt * 16 + col] = m0;
        }
        LDS_FENCE();
    }
    __syncthreads();
    // coalesced store: consecutive threads -> consecutive q, same channel
    for (int i = threadIdx.x; i < H2 * 16; i += 256) {
        int ch = i >> 4, q = i & 15;
        out1[((size_t)(b * H2 + ch)) * PP + qbase + q] = otile[q][ch];
    }
#undef PREFETCH
}

extern "C" void kernel_launch(void* const* d_in, const int* in_sizes, int n_in,
                              void* d_out, int out_size, void* d_ws, size_t ws_size,
                              hipStream_t stream) {
    const float* xyz  = (const float*)d_in[0];
    const float* feat = (const float*)d_in[1];
    const float* W1   = (const float*)d_in[2];
    const float* b1   = (const float*)d_in[3];
    const float* g1   = (const float*)d_in[4];
    const float* be1  = (const float*)d_in[5];
    const float* m1   = (const float*)d_in[6];
    const float* v1   = (const float*)d_in[7];
    const float* W2   = (const float*)d_in[8];
    const float* b2   = (const float*)d_in[9];
    const float* g2   = (const float*)d_in[10];
    const float* be2  = (const float*)d_in[11];
    const float* m2   = (const float*)d_in[12];
    const float* v2   = (const float*)d_in[13];

    char* ws = (char*)d_ws;
    float*          fxt  = (float*)(ws + OFF_FXT);
    float4*         pts4 = (float4*)(ws + OFF_PTS4);
    int*            knn  = (int*)(ws + OFF_KNN);
    unsigned short* w1p  = (unsigned short*)(ws + OFF_W1P);
    unsigned short* w2p  = (unsigned short*)(ws + OFF_W2P);
    float*          c1   = (float*)(ws + OFF_C1);
    float*          c2   = (float*)(ws + OFF_C2);

    float* out0 = (float*)d_out;
    float* out1 = out0 + (size_t)BB * PP * 3;
    float* out2 = out1 + (size_t)BB * H2 * PP;

    hipLaunchKernelGGL(k1_prep, dim3(1025), dim3(512), 0, stream,
                       xyz, feat, W1, b1, g1, be1, m1, v1, W2, b2, g2, be2, m2, v2,
                       fxt, pts4, out0, out2, w1p, w2p, c1, c2);
    hipLaunchKernelGGL(k2_knn, dim3(256), dim3(1024), 0, stream, pts4, knn);
    hipLaunchKernelGGL(k3_mlp, dim3(1024), dim3(256), 0, stream,
                       fxt, knn, w1p, w2p, c1, c2, out1);
}

// Round 9
// 203.931 us; speedup vs baseline: 1.0340x; 1.0340x over previous
//
#include <hip/hip_runtime.h>
#include <hip/hip_bf16.h>

// Problem constants
#define BB 8
#define NN 8192
#define CC 64
#define PP 2048
#define KK 16
#define H1 64
#define H2 128
#define K1PAD 160
#define K2PAD 72

typedef float  f32x4 __attribute__((ext_vector_type(4)));
typedef short  s16x8 __attribute__((ext_vector_type(8)));

// ---- workspace layout (bytes) ----
#define OFF_FXT   0u                    // B*N*68 f32 = 17,825,792
#define OFF_PTS4  17825792u             // B*N float4 = 2,097,152
#define OFF_KNN   19922944u             // B*P*16 int  = 1,048,576
#define OFF_W1P   20971520u             // 64*160 bf16 = 20,480
#define OFF_W2P   20992000u             // 128*72 bf16 = 18,432
#define OFF_C1    21010432u             // 64 f32
#define OFF_C2    21010688u             // 128 f32

#define FLTMAX 3.402823466e+38f

static __device__ __forceinline__ unsigned short bf16b(float v) {
    __hip_bfloat16 h = __float2bfloat16(v);
    return *reinterpret_cast<unsigned short*>(&h);
}
static __device__ __forceinline__ unsigned pk2(float a, float b) {
    return ((unsigned)bf16b(b) << 16) | (unsigned)bf16b(a);
}
// wave-local LDS fence: compiler barrier + LDS drain, NO vmcnt drain
#define LDS_FENCE() asm volatile("s_waitcnt lgkmcnt(0)" ::: "memory")

// ---------------- K1 v2: prep + (merged) weight folding ----------------
__global__ __launch_bounds__(512) void k1_prep(const float* __restrict__ xyz,
                                               const float* __restrict__ feat,
                                               const float* __restrict__ W1, const float* __restrict__ b1,
                                               const float* __restrict__ g1, const float* __restrict__ be1,
                                               const float* __restrict__ m1, const float* __restrict__ v1,
                                               const float* __restrict__ W2, const float* __restrict__ b2,
                                               const float* __restrict__ g2, const float* __restrict__ be2,
                                               const float* __restrict__ m2, const float* __restrict__ v2,
                                               float* __restrict__ fxt,
                                               float4* __restrict__ pts4,
                                               float* __restrict__ out0,
                                               float* __restrict__ out2,
                                               unsigned short* __restrict__ w1p,
                                               unsigned short* __restrict__ w2p,
                                               float* __restrict__ c1, float* __restrict__ c2) {
    if (blockIdx.x >= 1024) {
        for (int i = threadIdx.x; i < 19648; i += 512) {
            if (i < 64 * K1PAD) {
                int n = i / K1PAD, c = i - n * K1PAD;
                float s = g1[n] * rsqrtf(v1[n] + 1e-5f);
                float val = 0.f;
                if (c < 67)                  val = W1[n * 134 + c] * s;
                else if (c >= 72 && c < 139) val = W1[n * 134 + (c - 5)] * s;
                w1p[i] = bf16b(val);
            } else if (i < 19456) {
                int j = i - 10240;
                int o = j / K2PAD, k = j - o * K2PAD;
                float s = g2[o] * rsqrtf(v2[o] + 1e-5f);
                w2p[j] = bf16b((k < 64) ? W2[o * 64 + k] * s : 0.f);
            } else if (i < 19520) {
                int l = i - 19456;
                float s = g1[l] * rsqrtf(v1[l] + 1e-5f);
                c1[l] = s * (b1[l] - m1[l]) + be1[l];
            } else {
                int p = i - 19520;
                float s = g2[p] * rsqrtf(v2[p] + 1e-5f);
                c2[p] = s * (b2[p] - m2[p]) + be2[p];
            }
        }
        return;
    }
    __shared__ float tile[68][65];
    int b  = blockIdx.x >> 7;
    int n0 = (blockIdx.x & 127) * 64;
    int tx = threadIdx.x & 63, ty = threadIdx.x >> 6;
    for (int c = ty; c < 68; c += 8) {
        float v;
        if (c < 64)       v = feat[((size_t)b * 64 + c) * NN + n0 + tx];
        else if (c < 67)  v = xyz[((size_t)b * NN + n0 + tx) * 3 + (c - 64)];
        else              v = 0.f;
        tile[c][tx] = v;
    }
    __syncthreads();
    size_t base = ((size_t)b * NN + n0) * 68;
    for (int e = threadIdx.x; e < 64 * 68; e += 512) {
        int nl = e / 68, c = e - nl * 68;
        fxt[base + e] = tile[c][nl];
    }
    if (threadIdx.x < 64) {
        int n = n0 + threadIdx.x;
        float x = tile[64][threadIdx.x], y = tile[65][threadIdx.x], z = tile[66][threadIdx.x];
        pts4[(size_t)b * NN + n] = make_float4(x, y, z, x * x + y * y + z * z);
        if (n0 < PP) out2[b * PP + n] = (float)n;
    }
    if (n0 < PP) {
        for (int e = threadIdx.x; e < 64 * 3; e += 512) {
            int nl = e / 3, d = e - nl * 3;
            out0[((size_t)b * PP + n0 + nl) * 3 + d] = tile[64 + d][nl];
        }
    }
}

// ---------------- K2 v7: exact KNN, independent half-waves + single merge ----
// 256 blocks x 1024 thr (16 waves). Wave pair (p, p+8) serves the same 8
// queries; wave h owns rows h*64..h*64+63 (64 ds_read_b128/wave for phase 1,
// half of v5, serving 8 queries). Each half INDEPENDENTLY: own threshold
// T_h (16th-smallest of its 64 lane-mins), register-prefix compaction (no
// atomics), rank-select its half-top-16 -> merge16[pair][q][half*16+rank].
// ONE final barrier, then each wave merges 4 queries (rank-select over 32).
__global__ __launch_bounds__(1024, 4) void k2_knn(const float4* __restrict__ pts4,
                                                  int* __restrict__ knn) {
    __shared__ float4 stage[8192];           // 128 KB
    __shared__ float2 scratch[16][64];       // 8 KB per-wave survivors
    __shared__ float2 merge16[8][8][32];     // 16 KB (pair, q, half*16+rank)
    int lane = threadIdx.x & 63;
    int wv   = threadIdx.x >> 6;
    int pair = wv & 7;
    int half = wv >> 3;
    int b    = blockIdx.x >> 5;
    int q0   = (blockIdx.x & 31) * 64;       // block's 64 queries
    int qw   = q0 + pair * 8;                // this wave-pair's 8 queries
    size_t pb = (size_t)b * NN;

    // query coefficients (8 per wave; both halves load the same 8)
    float4 qc = make_float4(0.f, 0.f, 0.f, 0.f);
    if (lane < 8) qc = pts4[pb + qw + lane];
    float qx2 = -2.f * qc.x, qy2 = -2.f * qc.y, qz2 = -2.f * qc.z;
    float bx[8], by[8], bz[8];
#pragma unroll
    for (int q = 0; q < 8; ++q) {
        bx[q] = __shfl(qx2, q); by[q] = __shfl(qy2, q); bz[q] = __shfl(qz2, q);
    }

    // stage all 8192 points, swizzled slot(r,c) = r*64 + ((c + (r>>1)) & 63)
#pragma unroll
    for (int i = 0; i < 8; ++i) {
        int p = i * 1024 + threadIdx.x;
        float4 v = pts4[pb + p];
        int r = p >> 6, c = p & 63;
        stage[(r << 6) | ((c + (r >> 1)) & 63)] = v;
    }
    __syncthreads();

    // Phase 1: lane owns row (half*64 + lane): 64 candidates, 8 queries
    int row = half * 64 + lane;
    int rot = (row >> 1) & 63;
    int rowbase = row << 6;
    float m[8];
#pragma unroll
    for (int q = 0; q < 8; ++q) m[q] = FLTMAX;
#pragma unroll
    for (int j8 = 0; j8 < 8; ++j8) {
        float4 cc[8];
#pragma unroll
        for (int i = 0; i < 8; ++i)
            cc[i] = stage[rowbase | ((j8 * 8 + i + rot) & 63)];
#pragma unroll
        for (int q = 0; q < 8; ++q) {
            float x = bx[q], y = by[q], z = bz[q];
#pragma unroll
            for (int i = 0; i < 8; i += 2) {
                float e0 = fmaf(z, cc[i].z, fmaf(y, cc[i].y, fmaf(x, cc[i].x, cc[i].w)));
                float e1 = fmaf(z, cc[i+1].z, fmaf(y, cc[i+1].y, fmaf(x, cc[i+1].x, cc[i+1].w)));
                m[q] = fminf(fminf(m[q], e0), e1);
            }
        }
    }

    // own per-half thresholds: 16th smallest of 64 lane-mins (8-wide bitonic)
    float sv[8];
#pragma unroll
    for (int q = 0; q < 8; ++q) sv[q] = m[q];
#pragma unroll
    for (int k = 2; k <= 64; k <<= 1) {
#pragma unroll
        for (int j = k >> 1; j > 0; j >>= 1) {
            bool keepMin = (((lane & k) == 0) == ((lane & j) == 0));
#pragma unroll
            for (int q = 0; q < 8; ++q) {
                float p = __shfl_xor(sv[q], j, 64);
                sv[q] = keepMin ? fminf(sv[q], p) : fmaxf(sv[q], p);
            }
        }
    }
    float T[8];
    unsigned long long rm[8];
#pragma unroll
    for (int q = 0; q < 8; ++q) {
        T[q] = __shfl(sv[q], 15, 64);
        rm[q] = __ballot(m[q] <= T[q]);
    }

    unsigned long long below = (lane == 63) ? 0x7FFFFFFFFFFFFFFFull
                                            : ((1ull << lane) - 1ull);
    // per query: rescan own half, compact (register prefix), half-top-16
#pragma unroll 1
    for (int q = 0; q < 8; ++q) {
        float x = bx[q], y = by[q], z = bz[q], tq = T[q];
        unsigned long long r = rm[q];
        int cnt = 0;
        while (r) {
            int sl = __ffsll((long long)r) - 1; r &= r - 1;
            int rw = half * 64 + sl;
            int rrot = (rw >> 1) & 63;
            float4 c = stage[(rw << 6) | ((lane + rrot) & 63)];
            float e = fmaf(z, c.z, fmaf(y, c.y, fmaf(x, c.x, c.w)));
            int n = (rw << 6) | lane;     // logical col == lane by construction
            unsigned long long bal = __ballot(e <= tq);
            if (e <= tq) {
                int pos = cnt + __popcll(bal & below);
                if (pos < 64)
                    scratch[wv][pos] = make_float2(e, __int_as_float(n));
            }
            cnt += __popcll(bal);
        }
        LDS_FENCE();
        int M = min(cnt, 64);
        float2 own = scratch[wv][lane];
        float di = (lane < M) ? own.x : FLTMAX;
        int   ni = __float_as_int(own.y);
        int rank = 0;
        const float2* buf = &scratch[wv][0];
#pragma unroll 4
        for (int j = 0; j < M; ++j) {
            float2 e = buf[j];
            int nj = __float_as_int(e.y);
            rank += (e.x < di || (e.x == di && nj < ni)) ? 1 : 0;
        }
        if (lane < M && rank < 16)
            merge16[pair][q][half * 16 + rank] = own;
        LDS_FENCE();   // order scratch reuse across queries
    }
    __syncthreads();

    // merge: wave wv handles block-local queries wv*4 .. wv*4+3
#pragma unroll
    for (int u = 0; u < 4; ++u) {
        int ql = wv * 4 + u;
        int pr = ql >> 3, qq = ql & 7;
        if (lane < 32) {
            float2 e = merge16[pr][qq][lane];
            float di = e.x; int ni = __float_as_int(e.y);
            int rank = 0;
            const float2* buf = &merge16[pr][qq][0];
#pragma unroll 4
            for (int j = 0; j < 32; ++j) {
                float2 o = buf[j];
                int nj = __float_as_int(o.y);
                rank += (o.x < di || (o.x == di && nj < ni)) ? 1 : 0;
            }
            if (rank < 16)
                knn[((size_t)(b * PP + q0 + ql)) * KK + rank] = ni;
        }
    }
}

// ---------------- K3 v4: no-spill 4-wave blocks, w1 in LDS, h1 overlay ----
__global__ __launch_bounds__(256, 2) void k3_mlp(const float* __restrict__ fxt,
                                                 const int* __restrict__ knn,
                                                 const unsigned short* __restrict__ w1p,
                                                 const unsigned short* __restrict__ w2p,
                                                 const float* __restrict__ c1,
                                                 const float* __restrict__ c2,
                                                 float* __restrict__ out1) {
    __shared__ __align__(16) char smem[4 * 5632];
    __shared__ float otile[16][132];
    __shared__ __align__(16) unsigned short w1lds[64 * 168];   // 21,504 B
    int lane = threadIdx.x & 63;
    int wv   = threadIdx.x >> 6;
    int b    = blockIdx.x & 7;        // XCD-aware batch assignment
    int qg   = blockIdx.x >> 3;
    int qbase = qg * 16;
    char* seg = smem + wv * 5632;
    float4* sh_t4 = (float4*)(seg + 5120);
    unsigned* sh_tbd = (unsigned*)(seg + 5392);
    unsigned short* h1l = (unsigned short*)(seg);              // overlaid on E
    const float4* fx4 = (const float4*)fxt;

    int col = lane & 15, quad = lane >> 4;
    int r = lane >> 2, s = lane & 3;

    // stage w1p (64x160) into LDS rows of stride 168 (bank-balanced fragments)
    {
        const unsigned* src = (const unsigned*)w1p;
        unsigned* dst = (unsigned*)w1lds;
        for (int t = threadIdx.x; t < 5120; t += 256) {
            int row = t / 80, c = t - row * 80;
            dst[row * 84 + c] = src[t];
        }
    }

    s16x8 w2f[2][8];
#pragma unroll
    for (int ks = 0; ks < 2; ++ks)
#pragma unroll
        for (int nt = 0; nt < 8; ++nt)
            w2f[ks][nt] = *(const s16x8*)(w2p + (nt * 16 + col) * K2PAD + ks * 32 + quad * 8);
    float c1v[4], c2v[8];
#pragma unroll
    for (int nt = 0; nt < 4; ++nt) c1v[nt] = c1[nt * 16 + col];
#pragma unroll
    for (int nt = 0; nt < 8; ++nt) c2v[nt] = c2[nt * 16 + col];

    // all 64 knn indices for this wave's 4 queries (contiguous load)
    int idxAll = knn[((size_t)(b * PP + qbase + wv * 4)) * KK + lane];

    __syncthreads();   // w1lds visible to all waves

    float4 cc[2][5];
    float4 tv[2];

#define PREFETCH(buf, qi_) {                                                  \
        int q_ = qbase + wv * 4 + (qi_);                                      \
        tv[buf] = make_float4(0.f, 0.f, 0.f, 0.f);                            \
        if (lane < 17) tv[buf] = fx4[((size_t)b * NN + q_) * 17 + lane];      \
        int nidx_ = __shfl(idxAll, (qi_) * 16 + r, 64);                       \
        const float4* rowp_ = fx4 + ((size_t)b * NN + nidx_) * 17;            \
        cc[buf][0] = rowp_[s];      cc[buf][1] = rowp_[4 + s];                \
        cc[buf][2] = rowp_[8 + s];  cc[buf][3] = rowp_[12 + s];               \
        cc[buf][4] = rowp_[16]; }

    PREFETCH(0, 0);

#pragma unroll
    for (int qi = 0; qi < 4; ++qi) {
        int cur = qi & 1, nxt = cur ^ 1;
        // stage t row
        if (lane < 17) {
            float4 v = tv[cur];
            sh_t4[lane] = v;
            sh_tbd[lane * 2]     = pk2(v.x, v.y);
            sh_tbd[lane * 2 + 1] = pk2(v.z, v.w);
        }
        LDS_FENCE();
        // build E row r from prefetched registers + re-zero E K-pads
        char* erow = seg + r * 320;
#pragma unroll
        for (int j = 0; j < 4; ++j) {
            int c4 = j * 4 + s;
            float4 v = cc[cur][j], t = sh_t4[c4];
            *(unsigned*)(erow + c4 * 8)     = pk2(v.x - t.x, v.y - t.y);
            *(unsigned*)(erow + c4 * 8 + 4) = pk2(v.z - t.z, v.w - t.w);
        }
        if (s == 0) {
            float4 v = cc[cur][4], t = sh_t4[16];
            *(unsigned*)(erow + 128) = pk2(v.x - t.x, v.y - t.y);
            *(unsigned*)(erow + 132) = pk2(v.z - t.z, v.w - t.w);
        }
        for (int j = s; j < 34; j += 4)
            *(unsigned*)(erow + 144 + j * 4) = sh_tbd[j];
#pragma unroll
        for (int i = lane; i < 192; i += 64) {            // E pad dwords
            int rr = i / 12, jj = i - rr * 12;
            int dw = (jj < 2) ? (34 + jj) : (68 + jj);
            *(unsigned*)(seg + rr * 320 + dw * 4) = 0u;
        }
        // kick next query's gather while GEMMs run
        if (qi < 3) PREFETCH(nxt, qi + 1);
        LDS_FENCE();
        // GEMM1: h1 = relu(E * W1^T + c1); B-fragments from w1lds
        f32x4 acc1[4];
#pragma unroll
        for (int nt = 0; nt < 4; ++nt) acc1[nt] = (f32x4){0.f, 0.f, 0.f, 0.f};
#pragma unroll
        for (int ks = 0; ks < 5; ++ks) {
            s16x8 a = *(const s16x8*)(seg + col * 320 + ks * 64 + quad * 16);
#pragma unroll
            for (int nt = 0; nt < 4; ++nt) {
                s16x8 bf = *(const s16x8*)(w1lds + (nt * 16 + col) * 168 + ks * 32 + quad * 8);
                acc1[nt] = __builtin_amdgcn_mfma_f32_16x16x32_bf16(a, bf, acc1[nt], 0, 0, 0);
            }
        }
        // write h1 (overlaid on E; E fully consumed by in-order LDS reads)
#pragma unroll
        for (int nt = 0; nt < 4; ++nt) {
#pragma unroll
            for (int rr = 0; rr < 4; ++rr) {
                float y = fmaxf(acc1[nt][rr] + c1v[nt], 0.f);
                h1l[(quad * 4 + rr) * K2PAD + nt * 16 + col] = bf16b(y);
            }
        }
        {   // re-zero h1 K-pad (cols 64..71): 16 rows x 4 dwords, 1/lane
            int rr = lane >> 2, dd = lane & 3;
            *(unsigned*)(seg + rr * 144 + 128 + dd * 4) = 0u;
        }
        LDS_FENCE();
        // GEMM2 + maxpool over 16 edges
        f32x4 acc2[8];
#pragma unroll
        for (int nt = 0; nt < 8; ++nt) acc2[nt] = (f32x4){0.f, 0.f, 0.f, 0.f};
#pragma unroll
        for (int ks = 0; ks < 2; ++ks) {
            s16x8 a = *(const s16x8*)(seg + col * 144 + ks * 64 + quad * 16);
#pragma unroll
            for (int nt = 0; nt < 8; ++nt)
                acc2[nt] = __builtin_amdgcn_mfma_f32_16x16x32_bf16(a, w2f[ks][nt], acc2[nt], 0, 0, 0);
        }
#pragma unroll
        for (int nt = 0; nt < 8; ++nt) {
            float m0 = fmaxf(fmaxf(acc2[nt][0], acc2[nt][1]), fmaxf(acc2[nt][2], acc2[nt][3]));
            m0 = m0 + c2v[nt];
            m0 = fmaxf(m0, 0.f);
            m0 = fmaxf(m0, __shfl_xor(m0, 16, 64));
            m0 = fmaxf(m0, __shfl_xor(m0, 32, 64));
            if (quad == 0)
                otile[wv * 4 + qi][nt * 16 + col] = m0;
        }
        LDS_FENCE();
    }
    __syncthreads();
    // coalesced store: consecutive threads -> consecutive q, same channel
    for (int i = threadIdx.x; i < H2 * 16; i += 256) {
        int ch = i >> 4, q = i & 15;
        out1[((size_t)(b * H2 + ch)) * PP + qbase + q] = otile[q][ch];
    }
#undef PREFETCH
}

extern "C" void kernel_launch(void* const* d_in, const int* in_sizes, int n_in,
                              void* d_out, int out_size, void* d_ws, size_t ws_size,
                              hipStream_t stream) {
    const float* xyz  = (const float*)d_in[0];
    const float* feat = (const float*)d_in[1];
    const float* W1   = (const float*)d_in[2];
    const float* b1   = (const float*)d_in[3];
    const float* g1   = (const float*)d_in[4];
    const float* be1  = (const float*)d_in[5];
    const float* m1   = (const float*)d_in[6];
    const float* v1   = (const float*)d_in[7];
    const float* W2   = (const float*)d_in[8];
    const float* b2   = (const float*)d_in[9];
    const float* g2   = (const float*)d_in[10];
    const float* be2  = (const float*)d_in[11];
    const float* m2   = (const float*)d_in[12];
    const float* v2   = (const float*)d_in[13];

    char* ws = (char*)d_ws;
    float*          fxt  = (float*)(ws + OFF_FXT);
    float4*         pts4 = (float4*)(ws + OFF_PTS4);
    int*            knn  = (int*)(ws + OFF_KNN);
    unsigned short* w1p  = (unsigned short*)(ws + OFF_W1P);
    unsigned short* w2p  = (unsigned short*)(ws + OFF_W2P);
    float*          c1   = (float*)(ws + OFF_C1);
    float*          c2   = (float*)(ws + OFF_C2);

    float* out0 = (float*)d_out;
    float* out1 = out0 + (size_t)BB * PP * 3;
    float* out2 = out1 + (size_t)BB * H2 * PP;

    hipLaunchKernelGGL(k1_prep, dim3(1025), dim3(512), 0, stream,
                       xyz, feat, W1, b1, g1, be1, m1, v1, W2, b2, g2, be2, m2, v2,
                       fxt, pts4, out0, out2, w1p, w2p, c1, c2);
    hipLaunchKernelGGL(k2_knn, dim3(256), dim3(1024), 0, stream, pts4, knn);
    hipLaunchKernelGGL(k3_mlp, dim3(1024), dim3(256), 0, stream,
                       fxt, knn, w1p, w2p, c1, c2, out1);
}

// Round 10
// 180.261 us; speedup vs baseline: 1.1698x; 1.1313x over previous
//
#include <hip/hip_runtime.h>
#include <hip/hip_bf16.h>

// Problem constants
#define BB 8
#define NN 8192
#define CC 64
#define PP 2048
#define KK 16
#define H1 64
#define H2 128
#define K1PAD 160
#define K2PAD 72

typedef float  f32x4 __attribute__((ext_vector_type(4)));
typedef short  s16x8 __attribute__((ext_vector_type(8)));

// ---- workspace layout (bytes) ----
#define OFF_FXT   0u                    // B*N*68 f32 = 17,825,792
#define OFF_PTS4  17825792u             // B*N float4 = 2,097,152
#define OFF_KNN   19922944u             // B*P*16 int  = 1,048,576
#define OFF_W1P   20971520u             // 64*160 bf16 = 20,480
#define OFF_W2P   20992000u             // 128*72 bf16 = 18,432
#define OFF_C1    21010432u             // 64 f32
#define OFF_C2    21010688u             // 128 f32

#define FLTMAX 3.402823466e+38f

static __device__ __forceinline__ unsigned short bf16b(float v) {
    __hip_bfloat16 h = __float2bfloat16(v);
    return *reinterpret_cast<unsigned short*>(&h);
}
static __device__ __forceinline__ unsigned pk2(float a, float b) {
    return ((unsigned)bf16b(b) << 16) | (unsigned)bf16b(a);
}
// wave-local LDS fence: compiler barrier + LDS drain, NO vmcnt drain
#define LDS_FENCE() asm volatile("s_waitcnt lgkmcnt(0)" ::: "memory")

// ---------------- K1 v2: prep + (merged) weight folding ----------------
__global__ __launch_bounds__(512) void k1_prep(const float* __restrict__ xyz,
                                               const float* __restrict__ feat,
                                               const float* __restrict__ W1, const float* __restrict__ b1,
                                               const float* __restrict__ g1, const float* __restrict__ be1,
                                               const float* __restrict__ m1, const float* __restrict__ v1,
                                               const float* __restrict__ W2, const float* __restrict__ b2,
                                               const float* __restrict__ g2, const float* __restrict__ be2,
                                               const float* __restrict__ m2, const float* __restrict__ v2,
                                               float* __restrict__ fxt,
                                               float4* __restrict__ pts4,
                                               float* __restrict__ out0,
                                               float* __restrict__ out2,
                                               unsigned short* __restrict__ w1p,
                                               unsigned short* __restrict__ w2p,
                                               float* __restrict__ c1, float* __restrict__ c2) {
    if (blockIdx.x >= 1024) {
        for (int i = threadIdx.x; i < 19648; i += 512) {
            if (i < 64 * K1PAD) {
                int n = i / K1PAD, c = i - n * K1PAD;
                float s = g1[n] * rsqrtf(v1[n] + 1e-5f);
                float val = 0.f;
                if (c < 67)                  val = W1[n * 134 + c] * s;
                else if (c >= 72 && c < 139) val = W1[n * 134 + (c - 5)] * s;
                w1p[i] = bf16b(val);
            } else if (i < 19456) {
                int j = i - 10240;
                int o = j / K2PAD, k = j - o * K2PAD;
                float s = g2[o] * rsqrtf(v2[o] + 1e-5f);
                w2p[j] = bf16b((k < 64) ? W2[o * 64 + k] * s : 0.f);
            } else if (i < 19520) {
                int l = i - 19456;
                float s = g1[l] * rsqrtf(v1[l] + 1e-5f);
                c1[l] = s * (b1[l] - m1[l]) + be1[l];
            } else {
                int p = i - 19520;
                float s = g2[p] * rsqrtf(v2[p] + 1e-5f);
                c2[p] = s * (b2[p] - m2[p]) + be2[p];
            }
        }
        return;
    }
    __shared__ float tile[68][65];
    int b  = blockIdx.x >> 7;
    int n0 = (blockIdx.x & 127) * 64;
    int tx = threadIdx.x & 63, ty = threadIdx.x >> 6;
    for (int c = ty; c < 68; c += 8) {
        float v;
        if (c < 64)       v = feat[((size_t)b * 64 + c) * NN + n0 + tx];
        else if (c < 67)  v = xyz[((size_t)b * NN + n0 + tx) * 3 + (c - 64)];
        else              v = 0.f;
        tile[c][tx] = v;
    }
    __syncthreads();
    size_t base = ((size_t)b * NN + n0) * 68;
    for (int e = threadIdx.x; e < 64 * 68; e += 512) {
        int nl = e / 68, c = e - nl * 68;
        fxt[base + e] = tile[c][nl];
    }
    if (threadIdx.x < 64) {
        int n = n0 + threadIdx.x;
        float x = tile[64][threadIdx.x], y = tile[65][threadIdx.x], z = tile[66][threadIdx.x];
        pts4[(size_t)b * NN + n] = make_float4(x, y, z, x * x + y * y + z * z);
        if (n0 < PP) out2[b * PP + n] = (float)n;
    }
    if (n0 < PP) {
        for (int e = threadIdx.x; e < 64 * 3; e += 512) {
            int nl = e / 3, d = e - nl * 3;
            out0[((size_t)b * PP + n0 + nl) * 3 + d] = tile[64 + d][nl];
        }
    }
}

// ---------------- K2 v5 (proven best): exact KNN; broadcast rank-select ----
// 256 blocks x 1024 thr, whole batch staged once (128 KB), one barrier.
// Lane owns rows 2L,2L+1; swizzle slot(r,c)=r*64+((c+(r>>1))&63) is
// conflict-free for staging, phase-1 and rescan (measured 0 conflicts).
// Tail: 4-interleaved value bitonic threshold, register-prefix compaction
// into per-wave scratch, broadcast-LDS rank-select (no long bpermute chains).
__global__ __launch_bounds__(1024, 2) void k2_knn(const float4* __restrict__ pts4,
                                                  int* __restrict__ knn) {
    __shared__ float4 stage[8192];           // 128 KB
    __shared__ float2 scratch[16][2][64];    // 16 KB dual per-wave buffers
    int lane = threadIdx.x & 63;
    int wv   = threadIdx.x >> 6;
    int b    = blockIdx.x >> 5;
    int q0   = (blockIdx.x & 31) * 64 + wv * 4;
    size_t pb = (size_t)b * NN;

    float4 qc = make_float4(0.f, 0.f, 0.f, 0.f);
    if (lane < 4) qc = pts4[pb + q0 + lane];
    float qx2 = -2.f * qc.x, qy2 = -2.f * qc.y, qz2 = -2.f * qc.z;
    float bx[4], by[4], bz[4];
#pragma unroll
    for (int q = 0; q < 4; ++q) {
        bx[q] = __shfl(qx2, q); by[q] = __shfl(qy2, q); bz[q] = __shfl(qz2, q);
    }

    // stage all 8192 points, swizzled slot(r,c) = r*64 + ((c + (r>>1)) & 63)
#pragma unroll
    for (int i = 0; i < 8; ++i) {
        int p = i * 1024 + threadIdx.x;
        float4 v = pts4[pb + p];
        int r = p >> 6, c = p & 63;
        stage[(r << 6) | ((c + (r >> 1)) & 63)] = v;
    }
    __syncthreads();   // the only block barrier

    // Phase 1: per-lane min over its 128 candidates (rows 2L, 2L+1)
    float m[4];
#pragma unroll
    for (int q = 0; q < 4; ++q) m[q] = FLTMAX;
#pragma unroll
    for (int rr = 0; rr < 2; ++rr) {
        int rowbase = (2 * lane + rr) << 6;
#pragma unroll
        for (int j8 = 0; j8 < 8; ++j8) {
            float4 cc[8];
#pragma unroll
            for (int i = 0; i < 8; ++i)
                cc[i] = stage[rowbase | ((j8 * 8 + i + lane) & 63)];
#pragma unroll
            for (int q = 0; q < 4; ++q) {
                float x = bx[q], y = by[q], z = bz[q];
#pragma unroll
                for (int i = 0; i < 8; i += 2) {
                    float e0 = fmaf(z, cc[i].z, fmaf(y, cc[i].y, fmaf(x, cc[i].x, cc[i].w)));
                    float e1 = fmaf(z, cc[i+1].z, fmaf(y, cc[i+1].y, fmaf(x, cc[i+1].x, cc[i+1].w)));
                    m[q] = fminf(fminf(m[q], e0), e1);
                }
            }
        }
    }

    // Interleaved threshold sorts: T[q] = 16th smallest of 64 lane-mins
    float sv0 = m[0], sv1 = m[1], sv2 = m[2], sv3 = m[3];
#pragma unroll
    for (int k = 2; k <= 64; k <<= 1) {
#pragma unroll
        for (int j = k >> 1; j > 0; j >>= 1) {
            bool keepMin = (((lane & k) == 0) == ((lane & j) == 0));
            float p0 = __shfl_xor(sv0, j, 64);
            float p1 = __shfl_xor(sv1, j, 64);
            float p2 = __shfl_xor(sv2, j, 64);
            float p3 = __shfl_xor(sv3, j, 64);
            sv0 = keepMin ? fminf(sv0, p0) : fmaxf(sv0, p0);
            sv1 = keepMin ? fminf(sv1, p1) : fmaxf(sv1, p1);
            sv2 = keepMin ? fminf(sv2, p2) : fmaxf(sv2, p2);
            sv3 = keepMin ? fminf(sv3, p3) : fmaxf(sv3, p3);
        }
    }
    float T[4];
    T[0] = __shfl(sv0, 15, 64); T[1] = __shfl(sv1, 15, 64);
    T[2] = __shfl(sv2, 15, 64); T[3] = __shfl(sv3, 15, 64);

    unsigned long long below = (lane == 63) ? 0x7FFFFFFFFFFFFFFFull
                                            : ((1ull << lane) - 1ull);
#pragma unroll
    for (int pr = 0; pr < 4; pr += 2) {
        int Ms[2];
        // rescan + ballot-prefix compaction into dual scratch buffers
#pragma unroll
        for (int u = 0; u < 2; ++u) {
            int q = pr + u;
            float x = bx[q], y = by[q], z = bz[q], tq = T[q];
            unsigned long long rm = __ballot(m[q] <= tq);
            int cnt = 0;
            while (rm) {
                int sl = __ffsll((long long)rm) - 1; rm &= rm - 1;
                int phys = (lane + sl) & 63;
                float4 c0 = stage[((2 * sl) << 6) | phys];
                float4 c1 = stage[((2 * sl + 1) << 6) | phys];
                float e0 = fmaf(z, c0.z, fmaf(y, c0.y, fmaf(x, c0.x, c0.w)));
                float e1 = fmaf(z, c1.z, fmaf(y, c1.y, fmaf(x, c1.x, c1.w)));
                unsigned long long b0 = __ballot(e0 <= tq);
                if (e0 <= tq) {
                    int pos = cnt + __popcll(b0 & below);
                    if (pos < 64)
                        scratch[wv][u][pos] = make_float2(e0, __int_as_float(sl * 128 + lane));
                }
                cnt += __popcll(b0);
                unsigned long long b1 = __ballot(e1 <= tq);
                if (e1 <= tq) {
                    int pos = cnt + __popcll(b1 & below);
                    if (pos < 64)
                        scratch[wv][u][pos] = make_float2(e1, __int_as_float(sl * 128 + 64 + lane));
                }
                cnt += __popcll(b1);
            }
            Ms[u] = min(cnt, 64);
        }
        LDS_FENCE();   // drain compaction writes before readback
        // rank-select both queries (broadcast LDS reads, pipelined VALU)
#pragma unroll
        for (int u = 0; u < 2; ++u) {
            int M = Ms[u];
            float2 own = scratch[wv][u][lane];
            float di = own.x; int ni = __float_as_int(own.y);
            int rank = 0;
            const float2* buf = &scratch[wv][u][0];
#pragma unroll 4
            for (int j = 0; j < M; ++j) {
                float2 e = buf[j];
                int nj = __float_as_int(e.y);
                rank += (e.x < di || (e.x == di && nj < ni)) ? 1 : 0;
            }
            if (lane < M && rank < 16)
                knn[((size_t)(b * PP + q0 + pr + u)) * KK + rank] = ni;
        }
        LDS_FENCE();   // order scratch reuse across pairs
    }
}

// ---------------- K3 v4: no-spill 4-wave blocks, w1 in LDS, h1 overlay ----
__global__ __launch_bounds__(256, 2) void k3_mlp(const float* __restrict__ fxt,
                                                 const int* __restrict__ knn,
                                                 const unsigned short* __restrict__ w1p,
                                                 const unsigned short* __restrict__ w2p,
                                                 const float* __restrict__ c1,
                                                 const float* __restrict__ c2,
                                                 float* __restrict__ out1) {
    __shared__ __align__(16) char smem[4 * 5632];
    __shared__ float otile[16][132];
    __shared__ __align__(16) unsigned short w1lds[64 * 168];   // 21,504 B
    int lane = threadIdx.x & 63;
    int wv   = threadIdx.x >> 6;
    int b    = blockIdx.x & 7;        // XCD-aware batch assignment
    int qg   = blockIdx.x >> 3;
    int qbase = qg * 16;
    char* seg = smem + wv * 5632;
    float4* sh_t4 = (float4*)(seg + 5120);
    unsigned* sh_tbd = (unsigned*)(seg + 5392);
    unsigned short* h1l = (unsigned short*)(seg);              // overlaid on E
    const float4* fx4 = (const float4*)fxt;

    int col = lane & 15, quad = lane >> 4;
    int r = lane >> 2, s = lane & 3;

    // stage w1p (64x160) into LDS rows of stride 168 (bank-balanced fragments)
    {
        const unsigned* src = (const unsigned*)w1p;
        unsigned* dst = (unsigned*)w1lds;
        for (int t = threadIdx.x; t < 5120; t += 256) {
            int row = t / 80, c = t - row * 80;
            dst[row * 84 + c] = src[t];
        }
    }

    s16x8 w2f[2][8];
#pragma unroll
    for (int ks = 0; ks < 2; ++ks)
#pragma unroll
        for (int nt = 0; nt < 8; ++nt)
            w2f[ks][nt] = *(const s16x8*)(w2p + (nt * 16 + col) * K2PAD + ks * 32 + quad * 8);
    float c1v[4], c2v[8];
#pragma unroll
    for (int nt = 0; nt < 4; ++nt) c1v[nt] = c1[nt * 16 + col];
#pragma unroll
    for (int nt = 0; nt < 8; ++nt) c2v[nt] = c2[nt * 16 + col];

    // all 64 knn indices for this wave's 4 queries (contiguous load)
    int idxAll = knn[((size_t)(b * PP + qbase + wv * 4)) * KK + lane];

    __syncthreads();   // w1lds visible to all waves

    float4 cc[2][5];
    float4 tv[2];

#define PREFETCH(buf, qi_) {                                                  \
        int q_ = qbase + wv * 4 + (qi_);                                      \
        tv[buf] = make_float4(0.f, 0.f, 0.f, 0.f);                            \
        if (lane < 17) tv[buf] = fx4[((size_t)b * NN + q_) * 17 + lane];      \
        int nidx_ = __shfl(idxAll, (qi_) * 16 + r, 64);                       \
        const float4* rowp_ = fx4 + ((size_t)b * NN + nidx_) * 17;            \
        cc[buf][0] = rowp_[s];      cc[buf][1] = rowp_[4 + s];                \
        cc[buf][2] = rowp_[8 + s];  cc[buf][3] = rowp_[12 + s];               \
        cc[buf][4] = rowp_[16]; }

    PREFETCH(0, 0);

#pragma unroll
    for (int qi = 0; qi < 4; ++qi) {
        int cur = qi & 1, nxt = cur ^ 1;
        // stage t row
        if (lane < 17) {
            float4 v = tv[cur];
            sh_t4[lane] = v;
            sh_tbd[lane * 2]     = pk2(v.x, v.y);
            sh_tbd[lane * 2 + 1] = pk2(v.z, v.w);
        }
        LDS_FENCE();
        // build E row r from prefetched registers + re-zero E K-pads
        char* erow = seg + r * 320;
#pragma unroll
        for (int j = 0; j < 4; ++j) {
            int c4 = j * 4 + s;
            float4 v = cc[cur][j], t = sh_t4[c4];
            *(unsigned*)(erow + c4 * 8)     = pk2(v.x - t.x, v.y - t.y);
            *(unsigned*)(erow + c4 * 8 + 4) = pk2(v.z - t.z, v.w - t.w);
        }
        if (s == 0) {
            float4 v = cc[cur][4], t = sh_t4[16];
            *(unsigned*)(erow + 128) = pk2(v.x - t.x, v.y - t.y);
            *(unsigned*)(erow + 132) = pk2(v.z - t.z, v.w - t.w);
        }
        for (int j = s; j < 34; j += 4)
            *(unsigned*)(erow + 144 + j * 4) = sh_tbd[j];
#pragma unroll
        for (int i = lane; i < 192; i += 64) {            // E pad dwords
            int rr = i / 12, jj = i - rr * 12;
            int dw = (jj < 2) ? (34 + jj) : (68 + jj);
            *(unsigned*)(seg + rr * 320 + dw * 4) = 0u;
        }
        // kick next query's gather while GEMMs run
        if (qi < 3) PREFETCH(nxt, qi + 1);
        LDS_FENCE();
        // GEMM1: h1 = relu(E * W1^T + c1); B-fragments from w1lds
        f32x4 acc1[4];
#pragma unroll
        for (int nt = 0; nt < 4; ++nt) acc1[nt] = (f32x4){0.f, 0.f, 0.f, 0.f};
#pragma unroll
        for (int ks = 0; ks < 5; ++ks) {
            s16x8 a = *(const s16x8*)(seg + col * 320 + ks * 64 + quad * 16);
#pragma unroll
            for (int nt = 0; nt < 4; ++nt) {
                s16x8 bf = *(const s16x8*)(w1lds + (nt * 16 + col) * 168 + ks * 32 + quad * 8);
                acc1[nt] = __builtin_amdgcn_mfma_f32_16x16x32_bf16(a, bf, acc1[nt], 0, 0, 0);
            }
        }
        // write h1 (overlaid on E; E fully consumed by in-order LDS reads)
#pragma unroll
        for (int nt = 0; nt < 4; ++nt) {
#pragma unroll
            for (int rr = 0; rr < 4; ++rr) {
                float y = fmaxf(acc1[nt][rr] + c1v[nt], 0.f);
                h1l[(quad * 4 + rr) * K2PAD + nt * 16 + col] = bf16b(y);
            }
        }
        {   // re-zero h1 K-pad (cols 64..71): 16 rows x 4 dwords, 1/lane
            int rr = lane >> 2, dd = lane & 3;
            *(unsigned*)(seg + rr * 144 + 128 + dd * 4) = 0u;
        }
        LDS_FENCE();
        // GEMM2 + maxpool over 16 edges
        f32x4 acc2[8];
#pragma unroll
        for (int nt = 0; nt < 8; ++nt) acc2[nt] = (f32x4){0.f, 0.f, 0.f, 0.f};
#pragma unroll
        for (int ks = 0; ks < 2; ++ks) {
            s16x8 a = *(const s16x8*)(seg + col * 144 + ks * 64 + quad * 16);
#pragma unroll
            for (int nt = 0; nt < 8; ++nt)
                acc2[nt] = __builtin_amdgcn_mfma_f32_16x16x32_bf16(a, w2f[ks][nt], acc2[nt], 0, 0, 0);
        }
#pragma unroll
        for (int nt = 0; nt < 8; ++nt) {
            float m0 = fmaxf(fmaxf(acc2[nt][0], acc2[nt][1]), fmaxf(acc2[nt][2], acc2[nt][3]));
            m0 = m0 + c2v[nt];
            m0 = fmaxf(m0, 0.f);
            m0 = fmaxf(m0, __shfl_xor(m0, 16, 64));
            m0 = fmaxf(m0, __shfl_xor(m0, 32, 64));
            if (quad == 0)
                otile[wv * 4 + qi][nt * 16 + col] = m0;
        }
        LDS_FENCE();
    }
    __syncthreads();
    // coalesced store: consecutive threads -> consecutive q, same channel
    for (int i = threadIdx.x; i < H2 * 16; i += 256) {
        int ch = i >> 4, q = i & 15;
        out1[((size_t)(b * H2 + ch)) * PP + qbase + q] = otile[q][ch];
    }
#undef PREFETCH
}

extern "C" void kernel_launch(void* const* d_in, const int* in_sizes, int n_in,
                              void* d_out, int out_size, void* d_ws, size_t ws_size,
                              hipStream_t stream) {
    const float* xyz  = (const float*)d_in[0];
    const float* feat = (const float*)d_in[1];
    const float* W1   = (const float*)d_in[2];
    const float* b1   = (const float*)d_in[3];
    const float* g1   = (const float*)d_in[4];
    const float* be1  = (const float*)d_in[5];
    const float* m1   = (const float*)d_in[6];
    const float* v1   = (const float*)d_in[7];
    const float* W2   = (const float*)d_in[8];
    const float* b2   = (const float*)d_in[9];
    const float* g2   = (const float*)d_in[10];
    const float* be2  = (const float*)d_in[11];
    const float* m2   = (const float*)d_in[12];
    const float* v2   = (const float*)d_in[13];

    char* ws = (char*)d_ws;
    float*          fxt  = (float*)(ws + OFF_FXT);
    float4*         pts4 = (float4*)(ws + OFF_PTS4);
    int*            knn  = (int*)(ws + OFF_KNN);
    unsigned short* w1p  = (unsigned short*)(ws + OFF_W1P);
    unsigned short* w2p  = (unsigned short*)(ws + OFF_W2P);
    float*          c1   = (float*)(ws + OFF_C1);
    float*          c2   = (float*)(ws + OFF_C2);

    float* out0 = (float*)d_out;
    float* out1 = out0 + (size_t)BB * PP * 3;
    float* out2 = out1 + (size_t)BB * H2 * PP;

    hipLaunchKernelGGL(k1_prep, dim3(1025), dim3(512), 0, stream,
                       xyz, feat, W1, b1, g1, be1, m1, v1, W2, b2, g2, be2, m2, v2,
                       fxt, pts4, out0, out2, w1p, w2p, c1, c2);
    hipLaunchKernelGGL(k2_knn, dim3(256), dim3(1024), 0, stream, pts4, knn);
    hipLaunchKernelGGL(k3_mlp, dim3(1024), dim3(256), 0, stream,
                       fxt, knn, w1p, w2p, c1, c2, out1);
}

// Round 11
// 169.209 us; speedup vs baseline: 1.2462x; 1.0653x over previous
//
#include <hip/hip_runtime.h>
#include <hip/hip_bf16.h>

// Problem constants
#define BB 8
#define NN 8192
#define CC 64
#define PP 2048
#define KK 16
#define H1 64
#define H2 128
#define K1PAD 160
#define K2PAD 72

typedef float  f32x4 __attribute__((ext_vector_type(4)));
typedef short  s16x8 __attribute__((ext_vector_type(8)));

// ---- workspace layout (bytes) ----
#define OFF_FXT   0u                    // B*N*68 f32 = 17,825,792
#define OFF_PTS4  17825792u             // B*N float4 = 2,097,152
#define OFF_KNN   19922944u             // B*P*16 int  = 1,048,576
#define OFF_W1P   20971520u             // 64*160 bf16 = 20,480
#define OFF_W2P   20992000u             // 128*72 bf16 = 18,432
#define OFF_C1    21010432u             // 64 f32
#define OFF_C2    21010688u             // 128 f32

#define FLTMAX 3.402823466e+38f

static __device__ __forceinline__ unsigned short bf16b(float v) {
    __hip_bfloat16 h = __float2bfloat16(v);
    return *reinterpret_cast<unsigned short*>(&h);
}
static __device__ __forceinline__ unsigned pk2(float a, float b) {
    return ((unsigned)bf16b(b) << 16) | (unsigned)bf16b(a);
}
// wave-local LDS fence: compiler barrier + LDS drain, NO vmcnt drain
#define LDS_FENCE() asm volatile("s_waitcnt lgkmcnt(0)" ::: "memory")

// ---------------- K0: fold BN into weights, write bf16 W1p/W2p + c1/c2 ----
__global__ void k0_weights(const float* __restrict__ W1, const float* __restrict__ b1,
                           const float* __restrict__ g1, const float* __restrict__ be1,
                           const float* __restrict__ m1, const float* __restrict__ v1,
                           const float* __restrict__ W2, const float* __restrict__ b2,
                           const float* __restrict__ g2, const float* __restrict__ be2,
                           const float* __restrict__ m2, const float* __restrict__ v2,
                           unsigned short* __restrict__ w1p, unsigned short* __restrict__ w2p,
                           float* __restrict__ c1, float* __restrict__ c2) {
    int i = blockIdx.x * 256 + threadIdx.x;
    if (i < 64 * K1PAD) {
        int n = i / K1PAD, c = i - n * K1PAD;
        float s = g1[n] * rsqrtf(v1[n] + 1e-5f);
        float val = 0.f;
        if (c < 67)                 val = W1[n * 134 + c] * s;
        else if (c >= 72 && c < 139) val = W1[n * 134 + (c - 5)] * s;
        w1p[i] = bf16b(val);
    }
    int j = i - 64 * K1PAD;
    if (j >= 0 && j < 128 * K2PAD) {
        int o = j / K2PAD, k = j - o * K2PAD;
        float s = g2[o] * rsqrtf(v2[o] + 1e-5f);
        w2p[j] = bf16b((k < 64) ? W2[o * 64 + k] * s : 0.f);
    }
    int l = i - (64 * K1PAD + 128 * K2PAD);
    if (l >= 0 && l < 64) {
        float s = g1[l] * rsqrtf(v1[l] + 1e-5f);
        c1[l] = s * (b1[l] - m1[l]) + be1[l];
    }
    int p = l - 64;
    if (p >= 0 && p < 128) {
        float s = g2[p] * rsqrtf(v2[p] + 1e-5f);
        c2[p] = s * (b2[p] - m2[p]) + be2[p];
    }
}

// ---------------- K1: transpose feat -> fxt[b][n][68], pts4, out0, out2 ----
__global__ __launch_bounds__(512) void k1_prep(const float* __restrict__ xyz,
                                               const float* __restrict__ feat,
                                               float* __restrict__ fxt,
                                               float4* __restrict__ pts4,
                                               float* __restrict__ out0,
                                               float* __restrict__ out2) {
    __shared__ float tile[68][65];
    int b  = blockIdx.x >> 7;
    int n0 = (blockIdx.x & 127) * 64;
    int tx = threadIdx.x & 63, ty = threadIdx.x >> 6;
    for (int c = ty; c < 68; c += 8) {
        float v;
        if (c < 64)       v = feat[((size_t)b * 64 + c) * NN + n0 + tx];
        else if (c < 67)  v = xyz[((size_t)b * NN + n0 + tx) * 3 + (c - 64)];
        else              v = 0.f;
        tile[c][tx] = v;
    }
    __syncthreads();
    size_t base = ((size_t)b * NN + n0) * 68;
    for (int e = threadIdx.x; e < 64 * 68; e += 512) {
        int nl = e / 68, c = e - nl * 68;
        fxt[base + e] = tile[c][nl];
    }
    if (threadIdx.x < 64) {
        int n = n0 + threadIdx.x;
        float x = tile[64][threadIdx.x], y = tile[65][threadIdx.x], z = tile[66][threadIdx.x];
        pts4[(size_t)b * NN + n] = make_float4(x, y, z, x * x + y * y + z * z);
        if (n0 < PP) out2[b * PP + n] = (float)n;
    }
    if (n0 < PP) {
        for (int e = threadIdx.x; e < 64 * 3; e += 512) {
            int nl = e / 3, d = e - nl * 3;
            out0[((size_t)b * PP + n0 + nl) * 3 + d] = tile[64 + d][nl];
        }
    }
}

// ---------------- K2 v5 (session best): exact KNN; broadcast rank-select ----
// 256 blocks x 1024 thr, whole batch staged once (128 KB), one barrier.
// Lane owns rows 2L,2L+1; swizzle slot(r,c)=r*64+((c+(r>>1))&63) is
// conflict-free for staging, phase-1 and rescan (measured 0 conflicts).
// Tail: 4-interleaved value bitonic threshold, register-prefix compaction
// into per-wave scratch, broadcast-LDS rank-select (no long bpermute chains).
__global__ __launch_bounds__(1024, 2) void k2_knn(const float4* __restrict__ pts4,
                                                  int* __restrict__ knn) {
    __shared__ float4 stage[8192];           // 128 KB
    __shared__ float2 scratch[16][2][64];    // 16 KB dual per-wave buffers
    int lane = threadIdx.x & 63;
    int wv   = threadIdx.x >> 6;
    int b    = blockIdx.x >> 5;
    int q0   = (blockIdx.x & 31) * 64 + wv * 4;
    size_t pb = (size_t)b * NN;

    float4 qc = make_float4(0.f, 0.f, 0.f, 0.f);
    if (lane < 4) qc = pts4[pb + q0 + lane];
    float qx2 = -2.f * qc.x, qy2 = -2.f * qc.y, qz2 = -2.f * qc.z;
    float bx[4], by[4], bz[4];
#pragma unroll
    for (int q = 0; q < 4; ++q) {
        bx[q] = __shfl(qx2, q); by[q] = __shfl(qy2, q); bz[q] = __shfl(qz2, q);
    }

    // stage all 8192 points, swizzled slot(r,c) = r*64 + ((c + (r>>1)) & 63)
#pragma unroll
    for (int i = 0; i < 8; ++i) {
        int p = i * 1024 + threadIdx.x;
        float4 v = pts4[pb + p];
        int r = p >> 6, c = p & 63;
        stage[(r << 6) | ((c + (r >> 1)) & 63)] = v;
    }
    __syncthreads();   // the only block barrier

    // Phase 1: per-lane min over its 128 candidates (rows 2L, 2L+1)
    float m[4];
#pragma unroll
    for (int q = 0; q < 4; ++q) m[q] = FLTMAX;
#pragma unroll
    for (int rr = 0; rr < 2; ++rr) {
        int rowbase = (2 * lane + rr) << 6;
#pragma unroll
        for (int j8 = 0; j8 < 8; ++j8) {
            float4 cc[8];
#pragma unroll
            for (int i = 0; i < 8; ++i)
                cc[i] = stage[rowbase | ((j8 * 8 + i + lane) & 63)];
#pragma unroll
            for (int q = 0; q < 4; ++q) {
                float x = bx[q], y = by[q], z = bz[q];
#pragma unroll
                for (int i = 0; i < 8; i += 2) {
                    float e0 = fmaf(z, cc[i].z, fmaf(y, cc[i].y, fmaf(x, cc[i].x, cc[i].w)));
                    float e1 = fmaf(z, cc[i+1].z, fmaf(y, cc[i+1].y, fmaf(x, cc[i+1].x, cc[i+1].w)));
                    m[q] = fminf(fminf(m[q], e0), e1);
                }
            }
        }
    }

    // Interleaved threshold sorts: T[q] = 16th smallest of 64 lane-mins
    float sv0 = m[0], sv1 = m[1], sv2 = m[2], sv3 = m[3];
#pragma unroll
    for (int k = 2; k <= 64; k <<= 1) {
#pragma unroll
        for (int j = k >> 1; j > 0; j >>= 1) {
            bool keepMin = (((lane & k) == 0) == ((lane & j) == 0));
            float p0 = __shfl_xor(sv0, j, 64);
            float p1 = __shfl_xor(sv1, j, 64);
            float p2 = __shfl_xor(sv2, j, 64);
            float p3 = __shfl_xor(sv3, j, 64);
            sv0 = keepMin ? fminf(sv0, p0) : fmaxf(sv0, p0);
            sv1 = keepMin ? fminf(sv1, p1) : fmaxf(sv1, p1);
            sv2 = keepMin ? fminf(sv2, p2) : fmaxf(sv2, p2);
            sv3 = keepMin ? fminf(sv3, p3) : fmaxf(sv3, p3);
        }
    }
    float T[4];
    T[0] = __shfl(sv0, 15, 64); T[1] = __shfl(sv1, 15, 64);
    T[2] = __shfl(sv2, 15, 64); T[3] = __shfl(sv3, 15, 64);

    unsigned long long below = (lane == 63) ? 0x7FFFFFFFFFFFFFFFull
                                            : ((1ull << lane) - 1ull);
#pragma unroll
    for (int pr = 0; pr < 4; pr += 2) {
        int Ms[2];
        // rescan + ballot-prefix compaction into dual scratch buffers
#pragma unroll
        for (int u = 0; u < 2; ++u) {
            int q = pr + u;
            float x = bx[q], y = by[q], z = bz[q], tq = T[q];
            unsigned long long rm = __ballot(m[q] <= tq);
            int cnt = 0;
            while (rm) {
                int sl = __ffsll((long long)rm) - 1; rm &= rm - 1;
                int phys = (lane + sl) & 63;
                float4 c0 = stage[((2 * sl) << 6) | phys];
                float4 c1 = stage[((2 * sl + 1) << 6) | phys];
                float e0 = fmaf(z, c0.z, fmaf(y, c0.y, fmaf(x, c0.x, c0.w)));
                float e1 = fmaf(z, c1.z, fmaf(y, c1.y, fmaf(x, c1.x, c1.w)));
                unsigned long long b0 = __ballot(e0 <= tq);
                if (e0 <= tq) {
                    int pos = cnt + __popcll(b0 & below);
                    if (pos < 64)
                        scratch[wv][u][pos] = make_float2(e0, __int_as_float(sl * 128 + lane));
                }
                cnt += __popcll(b0);
                unsigned long long b1 = __ballot(e1 <= tq);
                if (e1 <= tq) {
                    int pos = cnt + __popcll(b1 & below);
                    if (pos < 64)
                        scratch[wv][u][pos] = make_float2(e1, __int_as_float(sl * 128 + 64 + lane));
                }
                cnt += __popcll(b1);
            }
            Ms[u] = min(cnt, 64);
        }
        LDS_FENCE();   // drain compaction writes before readback
        // rank-select both queries (broadcast LDS reads, pipelined VALU)
#pragma unroll
        for (int u = 0; u < 2; ++u) {
            int M = Ms[u];
            float2 own = scratch[wv][u][lane];
            float di = own.x; int ni = __float_as_int(own.y);
            int rank = 0;
            const float2* buf = &scratch[wv][u][0];
#pragma unroll 4
            for (int j = 0; j < M; ++j) {
                float2 e = buf[j];
                int nj = __float_as_int(e.y);
                rank += (e.x < di || (e.x == di && nj < ni)) ? 1 : 0;
            }
            if (lane < M && rank < 16)
                knn[((size_t)(b * PP + q0 + pr + u)) * KK + rank] = ni;
        }
        LDS_FENCE();   // order scratch reuse across pairs
    }
}

// ---------------- K3 v4: no-spill 4-wave blocks, w1 in LDS, h1 overlay ----
__global__ __launch_bounds__(256, 2) void k3_mlp(const float* __restrict__ fxt,
                                                 const int* __restrict__ knn,
                                                 const unsigned short* __restrict__ w1p,
                                                 const unsigned short* __restrict__ w2p,
                                                 const float* __restrict__ c1,
                                                 const float* __restrict__ c2,
                                                 float* __restrict__ out1) {
    __shared__ __align__(16) char smem[4 * 5632];
    __shared__ float otile[16][132];
    __shared__ __align__(16) unsigned short w1lds[64 * 168];   // 21,504 B
    int lane = threadIdx.x & 63;
    int wv   = threadIdx.x >> 6;
    int b    = blockIdx.x & 7;        // XCD-aware batch assignment
    int qg   = blockIdx.x >> 3;
    int qbase = qg * 16;
    char* seg = smem + wv * 5632;
    float4* sh_t4 = (float4*)(seg + 5120);
    unsigned* sh_tbd = (unsigned*)(seg + 5392);
    unsigned short* h1l = (unsigned short*)(seg);              // overlaid on E
    const float4* fx4 = (const float4*)fxt;

    int col = lane & 15, quad = lane >> 4;
    int r = lane >> 2, s = lane & 3;

    // stage w1p (64x160) into LDS rows of stride 168 (bank-balanced fragments)
    {
        const unsigned* src = (const unsigned*)w1p;
        unsigned* dst = (unsigned*)w1lds;
        for (int t = threadIdx.x; t < 5120; t += 256) {
            int row = t / 80, c = t - row * 80;
            dst[row * 84 + c] = src[t];
        }
    }

    s16x8 w2f[2][8];
#pragma unroll
    for (int ks = 0; ks < 2; ++ks)
#pragma unroll
        for (int nt = 0; nt < 8; ++nt)
            w2f[ks][nt] = *(const s16x8*)(w2p + (nt * 16 + col) * K2PAD + ks * 32 + quad * 8);
    float c1v[4], c2v[8];
#pragma unroll
    for (int nt = 0; nt < 4; ++nt) c1v[nt] = c1[nt * 16 + col];
#pragma unroll
    for (int nt = 0; nt < 8; ++nt) c2v[nt] = c2[nt * 16 + col];

    // all 64 knn indices for this wave's 4 queries (contiguous load)
    int idxAll = knn[((size_t)(b * PP + qbase + wv * 4)) * KK + lane];

    __syncthreads();   // w1lds visible to all waves

    float4 cc[2][5];
    float4 tv[2];

#define PREFETCH(buf, qi_) {                                                  \
        int q_ = qbase + wv * 4 + (qi_);                                      \
        tv[buf] = make_float4(0.f, 0.f, 0.f, 0.f);                            \
        if (lane < 17) tv[buf] = fx4[((size_t)b * NN + q_) * 17 + lane];      \
        int nidx_ = __shfl(idxAll, (qi_) * 16 + r, 64);                       \
        const float4* rowp_ = fx4 + ((size_t)b * NN + nidx_) * 17;            \
        cc[buf][0] = rowp_[s];      cc[buf][1] = rowp_[4 + s];                \
        cc[buf][2] = rowp_[8 + s];  cc[buf][3] = rowp_[12 + s];               \
        cc[buf][4] = rowp_[16]; }

    PREFETCH(0, 0);

#pragma unroll
    for (int qi = 0; qi < 4; ++qi) {
        int cur = qi & 1, nxt = cur ^ 1;
        // stage t row
        if (lane < 17) {
            float4 v = tv[cur];
            sh_t4[lane] = v;
            sh_tbd[lane * 2]     = pk2(v.x, v.y);
            sh_tbd[lane * 2 + 1] = pk2(v.z, v.w);
        }
        LDS_FENCE();
        // build E row r from prefetched registers + re-zero E K-pads
        char* erow = seg + r * 320;
#pragma unroll
        for (int j = 0; j < 4; ++j) {
            int c4 = j * 4 + s;
            float4 v = cc[cur][j], t = sh_t4[c4];
            *(unsigned*)(erow + c4 * 8)     = pk2(v.x - t.x, v.y - t.y);
            *(unsigned*)(erow + c4 * 8 + 4) = pk2(v.z - t.z, v.w - t.w);
        }
        if (s == 0) {
            float4 v = cc[cur][4], t = sh_t4[16];
            *(unsigned*)(erow + 128) = pk2(v.x - t.x, v.y - t.y);
            *(unsigned*)(erow + 132) = pk2(v.z - t.z, v.w - t.w);
        }
        for (int j = s; j < 34; j += 4)
            *(unsigned*)(erow + 144 + j * 4) = sh_tbd[j];
#pragma unroll
        for (int i = lane; i < 192; i += 64) {            // E pad dwords
            int rr = i / 12, jj = i - rr * 12;
            int dw = (jj < 2) ? (34 + jj) : (68 + jj);
            *(unsigned*)(seg + rr * 320 + dw * 4) = 0u;
        }
        // kick next query's gather while GEMMs run
        if (qi < 3) PREFETCH(nxt, qi + 1);
        LDS_FENCE();
        // GEMM1: h1 = relu(E * W1^T + c1); B-fragments from w1lds
        f32x4 acc1[4];
#pragma unroll
        for (int nt = 0; nt < 4; ++nt) acc1[nt] = (f32x4){0.f, 0.f, 0.f, 0.f};
#pragma unroll
        for (int ks = 0; ks < 5; ++ks) {
            s16x8 a = *(const s16x8*)(seg + col * 320 + ks * 64 + quad * 16);
#pragma unroll
            for (int nt = 0; nt < 4; ++nt) {
                s16x8 bf = *(const s16x8*)(w1lds + (nt * 16 + col) * 168 + ks * 32 + quad * 8);
                acc1[nt] = __builtin_amdgcn_mfma_f32_16x16x32_bf16(a, bf, acc1[nt], 0, 0, 0);
            }
        }
        // write h1 (overlaid on E; E fully consumed by in-order LDS reads)
#pragma unroll
        for (int nt = 0; nt < 4; ++nt) {
#pragma unroll
            for (int rr = 0; rr < 4; ++rr) {
                float y = fmaxf(acc1[nt][rr] + c1v[nt], 0.f);
                h1l[(quad * 4 + rr) * K2PAD + nt * 16 + col] = bf16b(y);
            }
        }
        {   // re-zero h1 K-pad (cols 64..71): 16 rows x 4 dwords, 1/lane
            int rr = lane >> 2, dd = lane & 3;
            *(unsigned*)(seg + rr * 144 + 128 + dd * 4) = 0u;
        }
        LDS_FENCE();
        // GEMM2 + maxpool over 16 edges
        f32x4 acc2[8];
#pragma unroll
        for (int nt = 0; nt < 8; ++nt) acc2[nt] = (f32x4){0.f, 0.f, 0.f, 0.f};
#pragma unroll
        for (int ks = 0; ks < 2; ++ks) {
            s16x8 a = *(const s16x8*)(seg + col * 144 + ks * 64 + quad * 16);
#pragma unroll
            for (int nt = 0; nt < 8; ++nt)
                acc2[nt] = __builtin_amdgcn_mfma_f32_16x16x32_bf16(a, w2f[ks][nt], acc2[nt], 0, 0, 0);
        }
#pragma unroll
        for (int nt = 0; nt < 8; ++nt) {
            float m0 = fmaxf(fmaxf(acc2[nt][0], acc2[nt][1]), fmaxf(acc2[nt][2], acc2[nt][3]));
            m0 = m0 + c2v[nt];
            m0 = fmaxf(m0, 0.f);
            m0 = fmaxf(m0, __shfl_xor(m0, 16, 64));
            m0 = fmaxf(m0, __shfl_xor(m0, 32, 64));
            if (quad == 0)
                otile[wv * 4 + qi][nt * 16 + col] = m0;
        }
        LDS_FENCE();
    }
    __syncthreads();
    // coalesced store: consecutive threads -> consecutive q, same channel
    for (int i = threadIdx.x; i < H2 * 16; i += 256) {
        int ch = i >> 4, q = i & 15;
        out1[((size_t)(b * H2 + ch)) * PP + qbase + q] = otile[q][ch];
    }
#undef PREFETCH
}

extern "C" void kernel_launch(void* const* d_in, const int* in_sizes, int n_in,
                              void* d_out, int out_size, void* d_ws, size_t ws_size,
                              hipStream_t stream) {
    const float* xyz  = (const float*)d_in[0];
    const float* feat = (const float*)d_in[1];
    const float* W1   = (const float*)d_in[2];
    const float* b1   = (const float*)d_in[3];
    const float* g1   = (const float*)d_in[4];
    const float* be1  = (const float*)d_in[5];
    const float* m1   = (const float*)d_in[6];
    const float* v1   = (const float*)d_in[7];
    const float* W2   = (const float*)d_in[8];
    const float* b2   = (const float*)d_in[9];
    const float* g2   = (const float*)d_in[10];
    const float* be2  = (const float*)d_in[11];
    const float* m2   = (const float*)d_in[12];
    const float* v2   = (const float*)d_in[13];

    char* ws = (char*)d_ws;
    float*          fxt  = (float*)(ws + OFF_FXT);
    float4*         pts4 = (float4*)(ws + OFF_PTS4);
    int*            knn  = (int*)(ws + OFF_KNN);
    unsigned short* w1p  = (unsigned short*)(ws + OFF_W1P);
    unsigned short* w2p  = (unsigned short*)(ws + OFF_W2P);
    float*          c1   = (float*)(ws + OFF_C1);
    float*          c2   = (float*)(ws + OFF_C2);

    float* out0 = (float*)d_out;
    float* out1 = out0 + (size_t)BB * PP * 3;
    float* out2 = out1 + (size_t)BB * H2 * PP;

    hipLaunchKernelGGL(k0_weights, dim3(77), dim3(256), 0, stream,
                       W1, b1, g1, be1, m1, v1, W2, b2, g2, be2, m2, v2,
                       w1p, w2p, c1, c2);
    hipLaunchKernelGGL(k1_prep, dim3(1024), dim3(512), 0, stream,
                       xyz, feat, fxt, pts4, out0, out2);
    hipLaunchKernelGGL(k2_knn, dim3(256), dim3(1024), 0, stream, pts4, knn);
    hipLaunchKernelGGL(k3_mlp, dim3(1024), dim3(256), 0, stream,
                       fxt, knn, w1p, w2p, c1, c2, out1);
}

// Round 12
// 166.300 us; speedup vs baseline: 1.2680x; 1.0175x over previous
//
#include <hip/hip_runtime.h>
#include <hip/hip_bf16.h>

// Problem constants
#define BB 8
#define NN 8192
#define CC 64
#define PP 2048
#define KK 16
#define H1 64
#define H2 128
#define K1PAD 160
#define K2PAD 72

typedef float  f32x4 __attribute__((ext_vector_type(4)));
typedef short  s16x8 __attribute__((ext_vector_type(8)));

// ---- workspace layout (bytes) ----
#define OFF_FXT   0u                    // B*N*68 f32 = 17,825,792
#define OFF_PTS4  17825792u             // B*N float4 = 2,097,152
#define OFF_KNN   19922944u             // B*P*16 int  = 1,048,576
#define OFF_W1P   20971520u             // 64*160 bf16 = 20,480
#define OFF_W2P   20992000u             // 128*72 bf16 = 18,432
#define OFF_C1    21010432u             // 64 f32
#define OFF_C2    21010688u             // 128 f32

#define FLTMAX 3.402823466e+38f

static __device__ __forceinline__ unsigned short bf16b(float v) {
    __hip_bfloat16 h = __float2bfloat16(v);
    return *reinterpret_cast<unsigned short*>(&h);
}
static __device__ __forceinline__ unsigned pk2(float a, float b) {
    return ((unsigned)bf16b(b) << 16) | (unsigned)bf16b(a);
}
// wave-local LDS fence: compiler barrier + LDS drain, NO vmcnt drain
#define LDS_FENCE() asm volatile("s_waitcnt lgkmcnt(0)" ::: "memory")

// ---------------- K1: transpose feat -> fxt[b][n][68], pts4, out0, out2 ----
__global__ __launch_bounds__(512) void k1_prep(const float* __restrict__ xyz,
                                               const float* __restrict__ feat,
                                               float* __restrict__ fxt,
                                               float4* __restrict__ pts4,
                                               float* __restrict__ out0,
                                               float* __restrict__ out2) {
    __shared__ float tile[68][65];
    int b  = blockIdx.x >> 7;
    int n0 = (blockIdx.x & 127) * 64;
    int tx = threadIdx.x & 63, ty = threadIdx.x >> 6;
    for (int c = ty; c < 68; c += 8) {
        float v;
        if (c < 64)       v = feat[((size_t)b * 64 + c) * NN + n0 + tx];
        else if (c < 67)  v = xyz[((size_t)b * NN + n0 + tx) * 3 + (c - 64)];
        else              v = 0.f;
        tile[c][tx] = v;
    }
    __syncthreads();
    size_t base = ((size_t)b * NN + n0) * 68;
    for (int e = threadIdx.x; e < 64 * 68; e += 512) {
        int nl = e / 68, c = e - nl * 68;
        fxt[base + e] = tile[c][nl];
    }
    if (threadIdx.x < 64) {
        int n = n0 + threadIdx.x;
        float x = tile[64][threadIdx.x], y = tile[65][threadIdx.x], z = tile[66][threadIdx.x];
        pts4[(size_t)b * NN + n] = make_float4(x, y, z, x * x + y * y + z * z);
        if (n0 < PP) out2[b * PP + n] = (float)n;
    }
    if (n0 < PP) {
        for (int e = threadIdx.x; e < 64 * 3; e += 512) {
            int nl = e / 3, d = e - nl * 3;
            out0[((size_t)b * PP + n0 + nl) * 3 + d] = tile[64 + d][nl];
        }
    }
}

// ---------------- K2 v5 + inlined weight fold (k0 absorbed) ----
// 256 blocks x 1024 thr, whole batch staged once (128 KB), one barrier.
// Weight folding (19,648 elems) is sliced 77/block and issued during the
// staging phase — its scattered loads hide under the staging latency, and
// the k2->k3 boundary sequences visibility for k3.
// Lane owns rows 2L,2L+1; swizzle slot(r,c)=r*64+((c+(r>>1))&63) is
// conflict-free for staging, phase-1 and rescan (measured 0 conflicts).
// Tail: 4-interleaved value bitonic threshold, register-prefix compaction
// into per-wave scratch, broadcast-LDS rank-select (no long bpermute chains).
__global__ __launch_bounds__(1024, 2) void k2_knn(const float4* __restrict__ pts4,
                                                  int* __restrict__ knn,
                                                  const float* __restrict__ W1, const float* __restrict__ b1,
                                                  const float* __restrict__ g1, const float* __restrict__ be1,
                                                  const float* __restrict__ m1, const float* __restrict__ v1,
                                                  const float* __restrict__ W2, const float* __restrict__ b2,
                                                  const float* __restrict__ g2, const float* __restrict__ be2,
                                                  const float* __restrict__ m2, const float* __restrict__ v2,
                                                  unsigned short* __restrict__ w1p,
                                                  unsigned short* __restrict__ w2p,
                                                  float* __restrict__ c1, float* __restrict__ c2) {
    __shared__ float4 stage[8192];           // 128 KB
    __shared__ float2 scratch[16][2][64];    // 16 KB dual per-wave buffers
    int lane = threadIdx.x & 63;
    int wv   = threadIdx.x >> 6;
    int b    = blockIdx.x >> 5;
    int q0   = (blockIdx.x & 31) * 64 + wv * 4;
    size_t pb = (size_t)b * NN;

    float4 qc = make_float4(0.f, 0.f, 0.f, 0.f);
    if (lane < 4) qc = pts4[pb + q0 + lane];
    float qx2 = -2.f * qc.x, qy2 = -2.f * qc.y, qz2 = -2.f * qc.z;
    float bx[4], by[4], bz[4];
#pragma unroll
    for (int q = 0; q < 4; ++q) {
        bx[q] = __shfl(qx2, q); by[q] = __shfl(qy2, q); bz[q] = __shfl(qz2, q);
    }

    // stage all 8192 points, swizzled slot(r,c) = r*64 + ((c + (r>>1)) & 63)
#pragma unroll
    for (int i = 0; i < 8; ++i) {
        int p = i * 1024 + threadIdx.x;
        float4 v = pts4[pb + p];
        int r = p >> 6, c = p & 63;
        stage[(r << 6) | ((c + (r >> 1)) & 63)] = v;
    }

    // weight fold slice (former k0): 77 elems/block, hidden in staging latency
    if (threadIdx.x < 77) {
        int i = blockIdx.x * 77 + threadIdx.x;
        if (i < 64 * K1PAD) {
            int n = i / K1PAD, c = i - n * K1PAD;
            float s = g1[n] * rsqrtf(v1[n] + 1e-5f);
            float val = 0.f;
            if (c < 67)                  val = W1[n * 134 + c] * s;
            else if (c >= 72 && c < 139) val = W1[n * 134 + (c - 5)] * s;
            w1p[i] = bf16b(val);
        } else if (i < 19456) {
            int j = i - 10240;
            int o = j / K2PAD, k = j - o * K2PAD;
            float s = g2[o] * rsqrtf(v2[o] + 1e-5f);
            w2p[j] = bf16b((k < 64) ? W2[o * 64 + k] * s : 0.f);
        } else if (i < 19520) {
            int l = i - 19456;
            float s = g1[l] * rsqrtf(v1[l] + 1e-5f);
            c1[l] = s * (b1[l] - m1[l]) + be1[l];
        } else if (i < 19648) {
            int p = i - 19520;
            float s = g2[p] * rsqrtf(v2[p] + 1e-5f);
            c2[p] = s * (b2[p] - m2[p]) + be2[p];
        }
    }
    __syncthreads();   // the only block barrier

    // Phase 1: per-lane min over its 128 candidates (rows 2L, 2L+1)
    float m[4];
#pragma unroll
    for (int q = 0; q < 4; ++q) m[q] = FLTMAX;
#pragma unroll
    for (int rr = 0; rr < 2; ++rr) {
        int rowbase = (2 * lane + rr) << 6;
#pragma unroll
        for (int j8 = 0; j8 < 8; ++j8) {
            float4 cc[8];
#pragma unroll
            for (int i = 0; i < 8; ++i)
                cc[i] = stage[rowbase | ((j8 * 8 + i + lane) & 63)];
#pragma unroll
            for (int q = 0; q < 4; ++q) {
                float x = bx[q], y = by[q], z = bz[q];
#pragma unroll
                for (int i = 0; i < 8; i += 2) {
                    float e0 = fmaf(z, cc[i].z, fmaf(y, cc[i].y, fmaf(x, cc[i].x, cc[i].w)));
                    float e1 = fmaf(z, cc[i+1].z, fmaf(y, cc[i+1].y, fmaf(x, cc[i+1].x, cc[i+1].w)));
                    m[q] = fminf(fminf(m[q], e0), e1);
                }
            }
        }
    }

    // Interleaved threshold sorts: T[q] = 16th smallest of 64 lane-mins
    float sv0 = m[0], sv1 = m[1], sv2 = m[2], sv3 = m[3];
#pragma unroll
    for (int k = 2; k <= 64; k <<= 1) {
#pragma unroll
        for (int j = k >> 1; j > 0; j >>= 1) {
            bool keepMin = (((lane & k) == 0) == ((lane & j) == 0));
            float p0 = __shfl_xor(sv0, j, 64);
            float p1 = __shfl_xor(sv1, j, 64);
            float p2 = __shfl_xor(sv2, j, 64);
            float p3 = __shfl_xor(sv3, j, 64);
            sv0 = keepMin ? fminf(sv0, p0) : fmaxf(sv0, p0);
            sv1 = keepMin ? fminf(sv1, p1) : fmaxf(sv1, p1);
            sv2 = keepMin ? fminf(sv2, p2) : fmaxf(sv2, p2);
            sv3 = keepMin ? fminf(sv3, p3) : fmaxf(sv3, p3);
        }
    }
    float T[4];
    T[0] = __shfl(sv0, 15, 64); T[1] = __shfl(sv1, 15, 64);
    T[2] = __shfl(sv2, 15, 64); T[3] = __shfl(sv3, 15, 64);

    unsigned long long below = (lane == 63) ? 0x7FFFFFFFFFFFFFFFull
                                            : ((1ull << lane) - 1ull);
#pragma unroll
    for (int pr = 0; pr < 4; pr += 2) {
        int Ms[2];
        // rescan + ballot-prefix compaction into dual scratch buffers
#pragma unroll
        for (int u = 0; u < 2; ++u) {
            int q = pr + u;
            float x = bx[q], y = by[q], z = bz[q], tq = T[q];
            unsigned long long rm = __ballot(m[q] <= tq);
            int cnt = 0;
            while (rm) {
                int sl = __ffsll((long long)rm) - 1; rm &= rm - 1;
                int phys = (lane + sl) & 63;
                float4 c0 = stage[((2 * sl) << 6) | phys];
                float4 c1v_ = stage[((2 * sl + 1) << 6) | phys];
                float e0 = fmaf(z, c0.z, fmaf(y, c0.y, fmaf(x, c0.x, c0.w)));
                float e1 = fmaf(z, c1v_.z, fmaf(y, c1v_.y, fmaf(x, c1v_.x, c1v_.w)));
                unsigned long long b0 = __ballot(e0 <= tq);
                if (e0 <= tq) {
                    int pos = cnt + __popcll(b0 & below);
                    if (pos < 64)
                        scratch[wv][u][pos] = make_float2(e0, __int_as_float(sl * 128 + lane));
                }
                cnt += __popcll(b0);
                unsigned long long b1 = __ballot(e1 <= tq);
                if (e1 <= tq) {
                    int pos = cnt + __popcll(b1 & below);
                    if (pos < 64)
                        scratch[wv][u][pos] = make_float2(e1, __int_as_float(sl * 128 + 64 + lane));
                }
                cnt += __popcll(b1);
            }
            Ms[u] = min(cnt, 64);
        }
        LDS_FENCE();   // drain compaction writes before readback
        // rank-select both queries (broadcast LDS reads, pipelined VALU)
#pragma unroll
        for (int u = 0; u < 2; ++u) {
            int M = Ms[u];
            float2 own = scratch[wv][u][lane];
            float di = own.x; int ni = __float_as_int(own.y);
            int rank = 0;
            const float2* buf = &scratch[wv][u][0];
#pragma unroll 4
            for (int j = 0; j < M; ++j) {
                float2 e = buf[j];
                int nj = __float_as_int(e.y);
                rank += (e.x < di || (e.x == di && nj < ni)) ? 1 : 0;
            }
            if (lane < M && rank < 16)
                knn[((size_t)(b * PP + q0 + pr + u)) * KK + rank] = ni;
        }
        LDS_FENCE();   // order scratch reuse across pairs
    }
}

// ---------------- K3 v4.1: no-spill 4-wave blocks, w1 in LDS, h1 overlay ----
// (v4 minus the dead h1 K-pad re-zero: GEMM2 A-fragments read elements 0..63
// of each 72-element h1 row only — cols 64..71 are never consumed.)
__global__ __launch_bounds__(256, 2) void k3_mlp(const float* __restrict__ fxt,
                                                 const int* __restrict__ knn,
                                                 const unsigned short* __restrict__ w1p,
                                                 const unsigned short* __restrict__ w2p,
                                                 const float* __restrict__ c1,
                                                 const float* __restrict__ c2,
                                                 float* __restrict__ out1) {
    __shared__ __align__(16) char smem[4 * 5632];
    __shared__ float otile[16][132];
    __shared__ __align__(16) unsigned short w1lds[64 * 168];   // 21,504 B
    int lane = threadIdx.x & 63;
    int wv   = threadIdx.x >> 6;
    int b    = blockIdx.x & 7;        // XCD-aware batch assignment
    int qg   = blockIdx.x >> 3;
    int qbase = qg * 16;
    char* seg = smem + wv * 5632;
    float4* sh_t4 = (float4*)(seg + 5120);
    unsigned* sh_tbd = (unsigned*)(seg + 5392);
    unsigned short* h1l = (unsigned short*)(seg);              // overlaid on E
    const float4* fx4 = (const float4*)fxt;

    int col = lane & 15, quad = lane >> 4;
    int r = lane >> 2, s = lane & 3;

    // stage w1p (64x160) into LDS rows of stride 168 (bank-balanced fragments)
    {
        const unsigned* src = (const unsigned*)w1p;
        unsigned* dst = (unsigned*)w1lds;
        for (int t = threadIdx.x; t < 5120; t += 256) {
            int row = t / 80, c = t - row * 80;
            dst[row * 84 + c] = src[t];
        }
    }

    s16x8 w2f[2][8];
#pragma unroll
    for (int ks = 0; ks < 2; ++ks)
#pragma unroll
        for (int nt = 0; nt < 8; ++nt)
            w2f[ks][nt] = *(const s16x8*)(w2p + (nt * 16 + col) * K2PAD + ks * 32 + quad * 8);
    float c1v[4], c2v[8];
#pragma unroll
    for (int nt = 0; nt < 4; ++nt) c1v[nt] = c1[nt * 16 + col];
#pragma unroll
    for (int nt = 0; nt < 8; ++nt) c2v[nt] = c2[nt * 16 + col];

    // all 64 knn indices for this wave's 4 queries (contiguous load)
    int idxAll = knn[((size_t)(b * PP + qbase + wv * 4)) * KK + lane];

    __syncthreads();   // w1lds visible to all waves

    float4 cc[2][5];
    float4 tv[2];

#define PREFETCH(buf, qi_) {                                                  \
        int q_ = qbase + wv * 4 + (qi_);                                      \
        tv[buf] = make_float4(0.f, 0.f, 0.f, 0.f);                            \
        if (lane < 17) tv[buf] = fx4[((size_t)b * NN + q_) * 17 + lane];      \
        int nidx_ = __shfl(idxAll, (qi_) * 16 + r, 64);                       \
        const float4* rowp_ = fx4 + ((size_t)b * NN + nidx_) * 17;            \
        cc[buf][0] = rowp_[s];      cc[buf][1] = rowp_[4 + s];                \
        cc[buf][2] = rowp_[8 + s];  cc[buf][3] = rowp_[12 + s];               \
        cc[buf][4] = rowp_[16]; }

    PREFETCH(0, 0);

#pragma unroll
    for (int qi = 0; qi < 4; ++qi) {
        int cur = qi & 1, nxt = cur ^ 1;
        // stage t row
        if (lane < 17) {
            float4 v = tv[cur];
            sh_t4[lane] = v;
            sh_tbd[lane * 2]     = pk2(v.x, v.y);
            sh_tbd[lane * 2 + 1] = pk2(v.z, v.w);
        }
        LDS_FENCE();
        // build E row r from prefetched registers + re-zero E K-pads
        char* erow = seg + r * 320;
#pragma unroll
        for (int j = 0; j < 4; ++j) {
            int c4 = j * 4 + s;
            float4 v = cc[cur][j], t = sh_t4[c4];
            *(unsigned*)(erow + c4 * 8)     = pk2(v.x - t.x, v.y - t.y);
            *(unsigned*)(erow + c4 * 8 + 4) = pk2(v.z - t.z, v.w - t.w);
        }
        if (s == 0) {
            float4 v = cc[cur][4], t = sh_t4[16];
            *(unsigned*)(erow + 128) = pk2(v.x - t.x, v.y - t.y);
            *(unsigned*)(erow + 132) = pk2(v.z - t.z, v.w - t.w);
        }
        for (int j = s; j < 34; j += 4)
            *(unsigned*)(erow + 144 + j * 4) = sh_tbd[j];
#pragma unroll
        for (int i = lane; i < 192; i += 64) {            // E pad dwords
            int rr = i / 12, jj = i - rr * 12;
            int dw = (jj < 2) ? (34 + jj) : (68 + jj);
            *(unsigned*)(seg + rr * 320 + dw * 4) = 0u;
        }
        // kick next query's gather while GEMMs run
        if (qi < 3) PREFETCH(nxt, qi + 1);
        LDS_FENCE();
        // GEMM1: h1 = relu(E * W1^T + c1); B-fragments from w1lds
        f32x4 acc1[4];
#pragma unroll
        for (int nt = 0; nt < 4; ++nt) acc1[nt] = (f32x4){0.f, 0.f, 0.f, 0.f};
#pragma unroll
        for (int ks = 0; ks < 5; ++ks) {
            s16x8 a = *(const s16x8*)(seg + col * 320 + ks * 64 + quad * 16);
#pragma unroll
            for (int nt = 0; nt < 4; ++nt) {
                s16x8 bf = *(const s16x8*)(w1lds + (nt * 16 + col) * 168 + ks * 32 + quad * 8);
                acc1[nt] = __builtin_amdgcn_mfma_f32_16x16x32_bf16(a, bf, acc1[nt], 0, 0, 0);
            }
        }
        // write h1 (overlaid on E; E fully consumed by in-order LDS reads)
#pragma unroll
        for (int nt = 0; nt < 4; ++nt) {
#pragma unroll
            for (int rr = 0; rr < 4; ++rr) {
                float y = fmaxf(acc1[nt][rr] + c1v[nt], 0.f);
                h1l[(quad * 4 + rr) * K2PAD + nt * 16 + col] = bf16b(y);
            }
        }
        LDS_FENCE();
        // GEMM2 + maxpool over 16 edges (A reads h1 elements 0..63 only)
        f32x4 acc2[8];
#pragma unroll
        for (int nt = 0; nt < 8; ++nt) acc2[nt] = (f32x4){0.f, 0.f, 0.f, 0.f};
#pragma unroll
        for (int ks = 0; ks < 2; ++ks) {
            s16x8 a = *(const s16x8*)(seg + col * 144 + ks * 64 + quad * 16);
#pragma unroll
            for (int nt = 0; nt < 8; ++nt)
                acc2[nt] = __builtin_amdgcn_mfma_f32_16x16x32_bf16(a, w2f[ks][nt], acc2[nt], 0, 0, 0);
        }
#pragma unroll
        for (int nt = 0; nt < 8; ++nt) {
            float m0 = fmaxf(fmaxf(acc2[nt][0], acc2[nt][1]), fmaxf(acc2[nt][2], acc2[nt][3]));
            m0 = m0 + c2v[nt];
            m0 = fmaxf(m0, 0.f);
            m0 = fmaxf(m0, __shfl_xor(m0, 16, 64));
            m0 = fmaxf(m0, __shfl_xor(m0, 32, 64));
            if (quad == 0)
                otile[wv * 4 + qi][nt * 16 + col] = m0;
        }
        LDS_FENCE();
    }
    __syncthreads();
    // coalesced store: consecutive threads -> consecutive q, same channel
    for (int i = threadIdx.x; i < H2 * 16; i += 256) {
        int ch = i >> 4, q = i & 15;
        out1[((size_t)(b * H2 + ch)) * PP + qbase + q] = otile[q][ch];
    }
#undef PREFETCH
}

extern "C" void kernel_launch(void* const* d_in, const int* in_sizes, int n_in,
                              void* d_out, int out_size, void* d_ws, size_t ws_size,
                              hipStream_t stream) {
    const float* xyz  = (const float*)d_in[0];
    const float* feat = (const float*)d_in[1];
    const float* W1   = (const float*)d_in[2];
    const float* b1   = (const float*)d_in[3];
    const float* g1   = (const float*)d_in[4];
    const float* be1  = (const float*)d_in[5];
    const float* m1   = (const float*)d_in[6];
    const float* v1   = (const float*)d_in[7];
    const float* W2   = (const float*)d_in[8];
    const float* b2   = (const float*)d_in[9];
    const float* g2   = (const float*)d_in[10];
    const float* be2  = (const float*)d_in[11];
    const float* m2   = (const float*)d_in[12];
    const float* v2   = (const float*)d_in[13];

    char* ws = (char*)d_ws;
    float*          fxt  = (float*)(ws + OFF_FXT);
    float4*         pts4 = (float4*)(ws + OFF_PTS4);
    int*            knn  = (int*)(ws + OFF_KNN);
    unsigned short* w1p  = (unsigned short*)(ws + OFF_W1P);
    unsigned short* w2p  = (unsigned short*)(ws + OFF_W2P);
    float*          c1   = (float*)(ws + OFF_C1);
    float*          c2   = (float*)(ws + OFF_C2);

    float* out0 = (float*)d_out;
    float* out1 = out0 + (size_t)BB * PP * 3;
    float* out2 = out1 + (size_t)BB * H2 * PP;

    hipLaunchKernelGGL(k1_prep, dim3(1024), dim3(512), 0, stream,
                       xyz, feat, fxt, pts4, out0, out2);
    hipLaunchKernelGGL(k2_knn, dim3(256), dim3(1024), 0, stream, pts4, knn,
                       W1, b1, g1, be1, m1, v1, W2, b2, g2, be2, m2, v2,
                       w1p, w2p, c1, c2);
    hipLaunchKernelGGL(k3_mlp, dim3(1024), dim3(256), 0, stream,
                       fxt, knn, w1p, w2p, c1, c2, out1);
}

// Round 13
// 164.261 us; speedup vs baseline: 1.2837x; 1.0124x over previous
//
#include <hip/hip_runtime.h>
#include <hip/hip_bf16.h>

// Problem constants
#define BB 8
#define NN 8192
#define CC 64
#define PP 2048
#define KK 16
#define H1 64
#define H2 128
#define K1PAD 160
#define K2PAD 72

typedef float  f32x4 __attribute__((ext_vector_type(4)));
typedef short  s16x8 __attribute__((ext_vector_type(8)));

// ---- workspace layout (bytes) ----
// fxtb: B*N rows of 72 bf16 (144 B, 16B-aligned) = 9,437,184 bytes
#define OFF_FXT   0u
#define OFF_PTS4  17825792u             // B*N float4 = 2,097,152
#define OFF_KNN   19922944u             // B*P*16 int  = 1,048,576
#define OFF_W1P   20971520u             // 64*160 bf16 = 20,480
#define OFF_W2P   20992000u             // 128*72 bf16 = 18,432
#define OFF_C1    21010432u             // 64 f32
#define OFF_C2    21010688u             // 128 f32

#define FLTMAX 3.402823466e+38f

static __device__ __forceinline__ unsigned short bf16b(float v) {
    __hip_bfloat16 h = __float2bfloat16(v);
    return *reinterpret_cast<unsigned short*>(&h);
}
static __device__ __forceinline__ unsigned pk2(float a, float b) {
    return ((unsigned)bf16b(b) << 16) | (unsigned)bf16b(a);
}
// diff of two bf16x2-packed dwords -> bf16x2-packed dword
static __device__ __forceinline__ unsigned dpk(unsigned v, unsigned t) {
    float v0 = __uint_as_float(v << 16), v1 = __uint_as_float(v & 0xffff0000u);
    float t0 = __uint_as_float(t << 16), t1 = __uint_as_float(t & 0xffff0000u);
    return pk2(v0 - t0, v1 - t1);
}
static __device__ __forceinline__ uint4 dpk4(uint4 v, uint4 t) {
    return make_uint4(dpk(v.x, t.x), dpk(v.y, t.y), dpk(v.z, t.z), dpk(v.w, t.w));
}
// wave-local LDS fence: compiler barrier + LDS drain, NO vmcnt drain
#define LDS_FENCE() asm volatile("s_waitcnt lgkmcnt(0)" ::: "memory")

// ---------------- K1: transpose feat -> fxtb (bf16 rows of 72), pts4, outs ----
__global__ __launch_bounds__(512) void k1_prep(const float* __restrict__ xyz,
                                               const float* __restrict__ feat,
                                               unsigned* __restrict__ fxtb,
                                               float4* __restrict__ pts4,
                                               float* __restrict__ out0,
                                               float* __restrict__ out2) {
    __shared__ float tile[72][65];
    int b  = blockIdx.x >> 7;
    int n0 = (blockIdx.x & 127) * 64;
    int tx = threadIdx.x & 63, ty = threadIdx.x >> 6;
    for (int c = ty; c < 72; c += 8) {
        float v;
        if (c < 64)       v = feat[((size_t)b * 64 + c) * NN + n0 + tx];
        else if (c < 67)  v = xyz[((size_t)b * NN + n0 + tx) * 3 + (c - 64)];
        else              v = 0.f;                 // pad cols 67..71
        tile[c][tx] = v;
    }
    __syncthreads();
    size_t base = ((size_t)b * NN + n0) * 36;      // 36 dwords (72 bf16) per row
    for (int e = threadIdx.x; e < 64 * 36; e += 512) {
        int nl = e / 36, c = e - nl * 36;
        fxtb[base + e] = pk2(tile[2 * c][nl], tile[2 * c + 1][nl]);
    }
    if (threadIdx.x < 64) {
        int n = n0 + threadIdx.x;
        float x = tile[64][threadIdx.x], y = tile[65][threadIdx.x], z = tile[66][threadIdx.x];
        pts4[(size_t)b * NN + n] = make_float4(x, y, z, x * x + y * y + z * z);
        if (n0 < PP) out2[b * PP + n] = (float)n;
    }
    if (n0 < PP) {
        for (int e = threadIdx.x; e < 64 * 3; e += 512) {
            int nl = e / 3, d = e - nl * 3;
            out0[((size_t)b * PP + n0 + nl) * 3 + d] = tile[64 + d][nl];
        }
    }
}

// ---------------- K2 v5 + inlined weight fold (k0 absorbed) ----
// 256 blocks x 1024 thr, whole batch staged once (128 KB), one barrier.
// Weight folding (19,648 elems) sliced 77/block, hidden in staging latency.
// Lane owns rows 2L,2L+1; swizzle slot(r,c)=r*64+((c+(r>>1))&63) is
// conflict-free for staging, phase-1 and rescan (measured 0 conflicts).
// Tail: 4-interleaved value bitonic threshold, register-prefix compaction
// into per-wave scratch, broadcast-LDS rank-select.
__global__ __launch_bounds__(1024, 2) void k2_knn(const float4* __restrict__ pts4,
                                                  int* __restrict__ knn,
                                                  const float* __restrict__ W1, const float* __restrict__ b1,
                                                  const float* __restrict__ g1, const float* __restrict__ be1,
                                                  const float* __restrict__ m1, const float* __restrict__ v1,
                                                  const float* __restrict__ W2, const float* __restrict__ b2,
                                                  const float* __restrict__ g2, const float* __restrict__ be2,
                                                  const float* __restrict__ m2, const float* __restrict__ v2,
                                                  unsigned short* __restrict__ w1p,
                                                  unsigned short* __restrict__ w2p,
                                                  float* __restrict__ c1, float* __restrict__ c2) {
    __shared__ float4 stage[8192];           // 128 KB
    __shared__ float2 scratch[16][2][64];    // 16 KB dual per-wave buffers
    int lane = threadIdx.x & 63;
    int wv   = threadIdx.x >> 6;
    int b    = blockIdx.x >> 5;
    int q0   = (blockIdx.x & 31) * 64 + wv * 4;
    size_t pb = (size_t)b * NN;

    float4 qc = make_float4(0.f, 0.f, 0.f, 0.f);
    if (lane < 4) qc = pts4[pb + q0 + lane];
    float qx2 = -2.f * qc.x, qy2 = -2.f * qc.y, qz2 = -2.f * qc.z;
    float bx[4], by[4], bz[4];
#pragma unroll
    for (int q = 0; q < 4; ++q) {
        bx[q] = __shfl(qx2, q); by[q] = __shfl(qy2, q); bz[q] = __shfl(qz2, q);
    }

    // stage all 8192 points, swizzled slot(r,c) = r*64 + ((c + (r>>1)) & 63)
#pragma unroll
    for (int i = 0; i < 8; ++i) {
        int p = i * 1024 + threadIdx.x;
        float4 v = pts4[pb + p];
        int r = p >> 6, c = p & 63;
        stage[(r << 6) | ((c + (r >> 1)) & 63)] = v;
    }

    // weight fold slice (former k0): 77 elems/block, hidden in staging latency
    if (threadIdx.x < 77) {
        int i = blockIdx.x * 77 + threadIdx.x;
        if (i < 64 * K1PAD) {
            int n = i / K1PAD, c = i - n * K1PAD;
            float s = g1[n] * rsqrtf(v1[n] + 1e-5f);
            float val = 0.f;
            if (c < 67)                  val = W1[n * 134 + c] * s;
            else if (c >= 72 && c < 139) val = W1[n * 134 + (c - 5)] * s;
            w1p[i] = bf16b(val);
        } else if (i < 19456) {
            int j = i - 10240;
            int o = j / K2PAD, k = j - o * K2PAD;
            float s = g2[o] * rsqrtf(v2[o] + 1e-5f);
            w2p[j] = bf16b((k < 64) ? W2[o * 64 + k] * s : 0.f);
        } else if (i < 19520) {
            int l = i - 19456;
            float s = g1[l] * rsqrtf(v1[l] + 1e-5f);
            c1[l] = s * (b1[l] - m1[l]) + be1[l];
        } else if (i < 19648) {
            int p = i - 19520;
            float s = g2[p] * rsqrtf(v2[p] + 1e-5f);
            c2[p] = s * (b2[p] - m2[p]) + be2[p];
        }
    }
    __syncthreads();   // the only block barrier

    // Phase 1: per-lane min over its 128 candidates (rows 2L, 2L+1)
    float m[4];
#pragma unroll
    for (int q = 0; q < 4; ++q) m[q] = FLTMAX;
#pragma unroll
    for (int rr = 0; rr < 2; ++rr) {
        int rowbase = (2 * lane + rr) << 6;
#pragma unroll
        for (int j8 = 0; j8 < 8; ++j8) {
            float4 cc[8];
#pragma unroll
            for (int i = 0; i < 8; ++i)
                cc[i] = stage[rowbase | ((j8 * 8 + i + lane) & 63)];
#pragma unroll
            for (int q = 0; q < 4; ++q) {
                float x = bx[q], y = by[q], z = bz[q];
#pragma unroll
                for (int i = 0; i < 8; i += 2) {
                    float e0 = fmaf(z, cc[i].z, fmaf(y, cc[i].y, fmaf(x, cc[i].x, cc[i].w)));
                    float e1 = fmaf(z, cc[i+1].z, fmaf(y, cc[i+1].y, fmaf(x, cc[i+1].x, cc[i+1].w)));
                    m[q] = fminf(fminf(m[q], e0), e1);
                }
            }
        }
    }

    // Interleaved threshold sorts: T[q] = 16th smallest of 64 lane-mins
    float sv0 = m[0], sv1 = m[1], sv2 = m[2], sv3 = m[3];
#pragma unroll
    for (int k = 2; k <= 64; k <<= 1) {
#pragma unroll
        for (int j = k >> 1; j > 0; j >>= 1) {
            bool keepMin = (((lane & k) == 0) == ((lane & j) == 0));
            float p0 = __shfl_xor(sv0, j, 64);
            float p1 = __shfl_xor(sv1, j, 64);
            float p2 = __shfl_xor(sv2, j, 64);
            float p3 = __shfl_xor(sv3, j, 64);
            sv0 = keepMin ? fminf(sv0, p0) : fmaxf(sv0, p0);
            sv1 = keepMin ? fminf(sv1, p1) : fmaxf(sv1, p1);
            sv2 = keepMin ? fminf(sv2, p2) : fmaxf(sv2, p2);
            sv3 = keepMin ? fminf(sv3, p3) : fmaxf(sv3, p3);
        }
    }
    float T[4];
    T[0] = __shfl(sv0, 15, 64); T[1] = __shfl(sv1, 15, 64);
    T[2] = __shfl(sv2, 15, 64); T[3] = __shfl(sv3, 15, 64);

    unsigned long long below = (lane == 63) ? 0x7FFFFFFFFFFFFFFFull
                                            : ((1ull << lane) - 1ull);
#pragma unroll
    for (int pr = 0; pr < 4; pr += 2) {
        int Ms[2];
        // rescan + ballot-prefix compaction into dual scratch buffers
#pragma unroll
        for (int u = 0; u < 2; ++u) {
            int q = pr + u;
            float x = bx[q], y = by[q], z = bz[q], tq = T[q];
            unsigned long long rm = __ballot(m[q] <= tq);
            int cnt = 0;
            while (rm) {
                int sl = __ffsll((long long)rm) - 1; rm &= rm - 1;
                int phys = (lane + sl) & 63;
                float4 c0 = stage[((2 * sl) << 6) | phys];
                float4 c1v_ = stage[((2 * sl + 1) << 6) | phys];
                float e0 = fmaf(z, c0.z, fmaf(y, c0.y, fmaf(x, c0.x, c0.w)));
                float e1 = fmaf(z, c1v_.z, fmaf(y, c1v_.y, fmaf(x, c1v_.x, c1v_.w)));
                unsigned long long b0 = __ballot(e0 <= tq);
                if (e0 <= tq) {
                    int pos = cnt + __popcll(b0 & below);
                    if (pos < 64)
                        scratch[wv][u][pos] = make_float2(e0, __int_as_float(sl * 128 + lane));
                }
                cnt += __popcll(b0);
                unsigned long long b1 = __ballot(e1 <= tq);
                if (e1 <= tq) {
                    int pos = cnt + __popcll(b1 & below);
                    if (pos < 64)
                        scratch[wv][u][pos] = make_float2(e1, __int_as_float(sl * 128 + 64 + lane));
                }
                cnt += __popcll(b1);
            }
            Ms[u] = min(cnt, 64);
        }
        LDS_FENCE();   // drain compaction writes before readback
        // rank-select both queries (broadcast LDS reads, pipelined VALU)
#pragma unroll
        for (int u = 0; u < 2; ++u) {
            int M = Ms[u];
            float2 own = scratch[wv][u][lane];
            float di = own.x; int ni = __float_as_int(own.y);
            int rank = 0;
            const float2* buf = &scratch[wv][u][0];
#pragma unroll 4
            for (int j = 0; j < M; ++j) {
                float2 e = buf[j];
                int nj = __float_as_int(e.y);
                rank += (e.x < di || (e.x == di && nj < ni)) ? 1 : 0;
            }
            if (lane < M && rank < 16)
                knn[((size_t)(b * PP + q0 + pr + u)) * KK + rank] = ni;
        }
        LDS_FENCE();   // order scratch reuse across pairs
    }
}

// ---------------- K3 v5: bf16 gather (half bytes), w1 in LDS, h1 overlay ----
// fxtb rows: 72 bf16 = 9 uint4 chunks. E row (160 bf16 = 20 chunks):
//   chunks 0..8  = diff (fxt pad cols 68..71 make E cols 67..71 auto-zero)
//   chunks 9..17 = tiled copy of t row (cols 140..143 auto-zero from t pad)
//   chunks 18,19 = zeroed each iteration (h1 overlay clobbers them)
__global__ __launch_bounds__(256, 2) void k3_mlp(const unsigned* __restrict__ fxtb,
                                                 const int* __restrict__ knn,
                                                 const unsigned short* __restrict__ w1p,
                                                 const unsigned short* __restrict__ w2p,
                                                 const float* __restrict__ c1,
                                                 const float* __restrict__ c2,
                                                 float* __restrict__ out1) {
    __shared__ __align__(16) char smem[4 * 5632];
    __shared__ float otile[16][132];
    __shared__ __align__(16) unsigned short w1lds[64 * 168];   // 21,504 B
    int lane = threadIdx.x & 63;
    int wv   = threadIdx.x >> 6;
    int b    = blockIdx.x & 7;        // XCD-aware batch assignment
    int qg   = blockIdx.x >> 3;
    int qbase = qg * 16;
    char* seg = smem + wv * 5632;
    uint4* sh_tc = (uint4*)(seg + 5120);                       // t row, 9 chunks
    unsigned short* h1l = (unsigned short*)(seg);              // overlaid on E
    const uint4* fx4 = (const uint4*)fxtb;                     // 9 chunks/row

    int col = lane & 15, quad = lane >> 4;
    int r = lane >> 2, s = lane & 3;

    // stage w1p (64x160) into LDS rows of stride 168 (bank-balanced fragments)
    {
        const unsigned* src = (const unsigned*)w1p;
        unsigned* dst = (unsigned*)w1lds;
        for (int t = threadIdx.x; t < 5120; t += 256) {
            int row = t / 80, c = t - row * 80;
            dst[row * 84 + c] = src[t];
        }
    }

    s16x8 w2f[2][8];
#pragma unroll
    for (int ks = 0; ks < 2; ++ks)
#pragma unroll
        for (int nt = 0; nt < 8; ++nt)
            w2f[ks][nt] = *(const s16x8*)(w2p + (nt * 16 + col) * K2PAD + ks * 32 + quad * 8);
    float c1v[4], c2v[8];
#pragma unroll
    for (int nt = 0; nt < 4; ++nt) c1v[nt] = c1[nt * 16 + col];
#pragma unroll
    for (int nt = 0; nt < 8; ++nt) c2v[nt] = c2[nt * 16 + col];

    // all 64 knn indices for this wave's 4 queries (contiguous load)
    int idxAll = knn[((size_t)(b * PP + qbase + wv * 4)) * KK + lane];

    __syncthreads();   // w1lds visible to all waves

    uint4 cc[2][3];
    uint4 tv[2];

#define PREFETCH(buf, qi_) {                                                  \
        int q_ = qbase + wv * 4 + (qi_);                                      \
        if (lane < 9) tv[buf] = fx4[((size_t)b * NN + q_) * 9 + lane];        \
        int nidx_ = __shfl(idxAll, (qi_) * 16 + r, 64);                       \
        const uint4* rowp_ = fx4 + ((size_t)b * NN + nidx_) * 9;              \
        cc[buf][0] = rowp_[s];                                                \
        cc[buf][1] = rowp_[4 + s];                                            \
        if (s == 0) cc[buf][2] = rowp_[8]; }

    PREFETCH(0, 0);

#pragma unroll
    for (int qi = 0; qi < 4; ++qi) {
        int cur = qi & 1, nxt = cur ^ 1;
        // stage t row (already bf16-packed)
        if (lane < 9) sh_tc[lane] = tv[cur];
        LDS_FENCE();
        // build E row r: diff chunks + tiled copy + zero tail chunks
        char* erow = seg + r * 320;
        {
            uint4 v = cc[cur][0], t = sh_tc[s];
            *(uint4*)(erow + s * 16) = dpk4(v, t);
            v = cc[cur][1]; t = sh_tc[4 + s];
            *(uint4*)(erow + (4 + s) * 16) = dpk4(v, t);
            if (s == 0) {
                v = cc[cur][2]; t = sh_tc[8];
                *(uint4*)(erow + 128) = dpk4(v, t);
            }
        }
        for (int j = s; j < 9; j += 4)
            *(uint4*)(erow + (9 + j) * 16) = sh_tc[j];
        if (s < 2)
            *(uint4*)(erow + (18 + s) * 16) = make_uint4(0u, 0u, 0u, 0u);
        // kick next query's gather while GEMMs run
        if (qi < 3) PREFETCH(nxt, qi + 1);
        LDS_FENCE();
        // GEMM1: h1 = relu(E * W1^T + c1); B-fragments from w1lds
        f32x4 acc1[4];
#pragma unroll
        for (int nt = 0; nt < 4; ++nt) acc1[nt] = (f32x4){0.f, 0.f, 0.f, 0.f};
#pragma unroll
        for (int ks = 0; ks < 5; ++ks) {
            s16x8 a = *(const s16x8*)(seg + col * 320 + ks * 64 + quad * 16);
#pragma unroll
            for (int nt = 0; nt < 4; ++nt) {
                s16x8 bf = *(const s16x8*)(w1lds + (nt * 16 + col) * 168 + ks * 32 + quad * 8);
                acc1[nt] = __builtin_amdgcn_mfma_f32_16x16x32_bf16(a, bf, acc1[nt], 0, 0, 0);
            }
        }
        // write h1 (overlaid on E; E fully consumed by in-order LDS reads)
#pragma unroll
        for (int nt = 0; nt < 4; ++nt) {
#pragma unroll
            for (int rr = 0; rr < 4; ++rr) {
                float y = fmaxf(acc1[nt][rr] + c1v[nt], 0.f);
                h1l[(quad * 4 + rr) * K2PAD + nt * 16 + col] = bf16b(y);
            }
        }
        LDS_FENCE();
        // GEMM2 + maxpool over 16 edges (A reads h1 elements 0..63 only)
        f32x4 acc2[8];
#pragma unroll
        for (int nt = 0; nt < 8; ++nt) acc2[nt] = (f32x4){0.f, 0.f, 0.f, 0.f};
#pragma unroll
        for (int ks = 0; ks < 2; ++ks) {
            s16x8 a = *(const s16x8*)(seg + col * 144 + ks * 64 + quad * 16);
#pragma unroll
            for (int nt = 0; nt < 8; ++nt)
                acc2[nt] = __builtin_amdgcn_mfma_f32_16x16x32_bf16(a, w2f[ks][nt], acc2[nt], 0, 0, 0);
        }
#pragma unroll
        for (int nt = 0; nt < 8; ++nt) {
            float m0 = fmaxf(fmaxf(acc2[nt][0], acc2[nt][1]), fmaxf(acc2[nt][2], acc2[nt][3]));
            m0 = m0 + c2v[nt];
            m0 = fmaxf(m0, 0.f);
            m0 = fmaxf(m0, __shfl_xor(m0, 16, 64));
            m0 = fmaxf(m0, __shfl_xor(m0, 32, 64));
            if (quad == 0)
                otile[wv * 4 + qi][nt * 16 + col] = m0;
        }
        LDS_FENCE();
    }
    __syncthreads();
    // coalesced store: consecutive threads -> consecutive q, same channel
    for (int i = threadIdx.x; i < H2 * 16; i += 256) {
        int ch = i >> 4, q = i & 15;
        out1[((size_t)(b * H2 + ch)) * PP + qbase + q] = otile[q][ch];
    }
#undef PREFETCH
}

extern "C" void kernel_launch(void* const* d_in, const int* in_sizes, int n_in,
                              void* d_out, int out_size, void* d_ws, size_t ws_size,
                              hipStream_t stream) {
    const float* xyz  = (const float*)d_in[0];
    const float* feat = (const float*)d_in[1];
    const float* W1   = (const float*)d_in[2];
    const float* b1   = (const float*)d_in[3];
    const float* g1   = (const float*)d_in[4];
    const float* be1  = (const float*)d_in[5];
    const float* m1   = (const float*)d_in[6];
    const float* v1   = (const float*)d_in[7];
    const float* W2   = (const float*)d_in[8];
    const float* b2   = (const float*)d_in[9];
    const float* g2   = (const float*)d_in[10];
    const float* be2  = (const float*)d_in[11];
    const float* m2   = (const float*)d_in[12];
    const float* v2   = (const float*)d_in[13];

    char* ws = (char*)d_ws;
    unsigned*       fxtb = (unsigned*)(ws + OFF_FXT);
    float4*         pts4 = (float4*)(ws + OFF_PTS4);
    int*            knn  = (int*)(ws + OFF_KNN);
    unsigned short* w1p  = (unsigned short*)(ws + OFF_W1P);
    unsigned short* w2p  = (unsigned short*)(ws + OFF_W2P);
    float*          c1   = (float*)(ws + OFF_C1);
    float*          c2   = (float*)(ws + OFF_C2);

    float* out0 = (float*)d_out;
    float* out1 = out0 + (size_t)BB * PP * 3;
    float* out2 = out1 + (size_t)BB * H2 * PP;

    hipLaunchKernelGGL(k1_prep, dim3(1024), dim3(512), 0, stream,
                       xyz, feat, fxtb, pts4, out0, out2);
    hipLaunchKernelGGL(k2_knn, dim3(256), dim3(1024), 0, stream, pts4, knn,
                       W1, b1, g1, be1, m1, v1, W2, b2, g2, be2, m2, v2,
                       w1p, w2p, c1, c2);
    hipLaunchKernelGGL(k3_mlp, dim3(1024), dim3(256), 0, stream,
                       fxtb, knn, w1p, w2p, c1, c2, out1);
}